// Round 1
// baseline (7759.916 us; speedup 1.0000x reference)
//
#include <hip/hip_runtime.h>
#include <math.h>

#define NB   2048   // batch
#define NSEQ 65     // sequence incl. origin
#define ND   256    // IN_DIM
#define NH   8      // heads
#define NL   256    // L
#define NS   64     // walk length (S-1)

__device__ __forceinline__ float sigmoidf_(float x) { return 1.0f / (1.0f + __expf(-x)); }

// ---------------------------------------------------------------------------
// Kernel 1: PK[h][s][l] = sum_d P[s][d] * Wk[h][d][l]   (batch-independent)
// ---------------------------------------------------------------------------
__global__ __launch_bounds__(256) void pk_kernel(const float* __restrict__ P,
                                                 const float* __restrict__ Wk,
                                                 float* __restrict__ PK) {
    int h = blockIdx.x >> 6;
    int s = blockIdx.x & 63;
    int t = threadIdx.x;
    __shared__ float p_s[ND];
    p_s[t] = P[s * ND + t];
    __syncthreads();
    const float* wk = Wk + h * (ND * NL) + t;
    float acc = 0.f;
    #pragma unroll 8
    for (int d = 0; d < ND; ++d) acc = fmaf(p_s[d], wk[d * NL], acc);
    PK[(h * NS + s) * NL + t] = acc;
}

// ---------------------------------------------------------------------------
// Kernel 2: per (b,h): q,v GEMMs + edge + score softmax + res
// thread t owns column l=t; acc_q/acc_v[s] in registers.
// ---------------------------------------------------------------------------
__global__ __launch_bounds__(256, 2) void attn_kernel(
        const float* __restrict__ x,
        const float* __restrict__ Wq,
        const float* __restrict__ Wk,
        const float* __restrict__ Wv,
        const float* __restrict__ W,
        const float* __restrict__ bias,
        const float* __restrict__ PK,
        float* __restrict__ res) {
    int h = blockIdx.x >> 11;          // h-major: concurrent blocks share a head
    int b = blockIdx.x & 2047;
    int t = threadIdx.x;

    __shared__ float walkT[128][68];   // [d-in-tile][s], pad 68 -> 16B-aligned rows
    __shared__ float origin_s[ND];
    __shared__ float red[4][NS];
    __shared__ float score_s[NS];

    const float* xb = x + b * (NSEQ * ND);
    origin_s[t] = xb[t];

    float acc_q[NS], acc_v[NS];
    #pragma unroll
    for (int s = 0; s < NS; ++s) { acc_q[s] = 0.f; acc_v[s] = 0.f; }
    float acc_ok = 0.f;

    const float* wq_p = Wq + h * (ND * NL) + t;
    const float* wk_p = Wk + h * (ND * NL) + t;
    const float* wv_p = Wv + h * (ND * NL) + t;

    for (int tile = 0; tile < 2; ++tile) {
        int d0 = tile * 128;
        __syncthreads();               // protect previous tile (and origin_s on tile 0)
        #pragma unroll
        for (int k = 0; k < 32; ++k) { // stage walk tile transposed: [d][s]
            int i = t + k * 256;
            int s = i >> 7;
            int d = i & 127;
            walkT[d][s] = xb[(1 + s) * ND + d0 + d];
        }
        __syncthreads();
        #pragma unroll 2
        for (int dd = 0; dd < 128; ++dd) {
            int d = d0 + dd;
            float wq = wq_p[d * NL];   // coalesced over t, L2-resident
            float wv = wv_p[d * NL];
            float wk = wk_p[d * NL];
            acc_ok = fmaf(origin_s[d], wk, acc_ok);
            const float4* wrow = (const float4*)(&walkT[dd][0]);  // broadcast reads
            #pragma unroll
            for (int s4 = 0; s4 < 16; ++s4) {
                float4 w4 = wrow[s4];
                acc_q[s4*4+0] = fmaf(w4.x, wq, acc_q[s4*4+0]);
                acc_q[s4*4+1] = fmaf(w4.y, wq, acc_q[s4*4+1]);
                acc_q[s4*4+2] = fmaf(w4.z, wq, acc_q[s4*4+2]);
                acc_q[s4*4+3] = fmaf(w4.w, wq, acc_q[s4*4+3]);
                acc_v[s4*4+0] = fmaf(w4.x, wv, acc_v[s4*4+0]);
                acc_v[s4*4+1] = fmaf(w4.y, wv, acc_v[s4*4+1]);
                acc_v[s4*4+2] = fmaf(w4.z, wv, acc_v[s4*4+2]);
                acc_v[s4*4+3] = fmaf(w4.w, wv, acc_v[s4*4+3]);
            }
        }
    }

    // edge contribution per (s, l=t), weighted by W[h,t]; reuse acc_q storage
    float w_ht = W[h * NL + t];        // W is (H, L, 1)
    float bh   = bias[h];
    const float* pk_p = PK + (h * NS) * NL + t;
    #pragma unroll
    for (int s = 0; s < NS; ++s) {
        float qs = sigmoidf_(acc_q[s]);
        float ks = sigmoidf_(acc_ok + pk_p[s * NL]);
        acc_q[s] = (__cosf(ks * qs) + bh) * w_ht;
    }

    // reduce over l (all 256 threads) for each s
    int wave = t >> 6;
    int lane = t & 63;
    #pragma unroll
    for (int s = 0; s < NS; ++s) {
        float v = acc_q[s];
        v += __shfl_xor(v, 1, 64);
        v += __shfl_xor(v, 2, 64);
        v += __shfl_xor(v, 4, 64);
        v += __shfl_xor(v, 8, 64);
        v += __shfl_xor(v, 16, 64);
        v += __shfl_xor(v, 32, 64);
        if (lane == s) red[wave][s] = v;   // s is a compile-time constant here
    }
    __syncthreads();

    // softmax over s in wave 0
    if (t < NS) {
        float sc = red[0][t] + red[1][t] + red[2][t] + red[3][t];
        float m = sc;
        m = fmaxf(m, __shfl_xor(m, 1, 64));
        m = fmaxf(m, __shfl_xor(m, 2, 64));
        m = fmaxf(m, __shfl_xor(m, 4, 64));
        m = fmaxf(m, __shfl_xor(m, 8, 64));
        m = fmaxf(m, __shfl_xor(m, 16, 64));
        m = fmaxf(m, __shfl_xor(m, 32, 64));
        float e = __expf(sc - m);
        float se = e;
        se += __shfl_xor(se, 1, 64);
        se += __shfl_xor(se, 2, 64);
        se += __shfl_xor(se, 4, 64);
        se += __shfl_xor(se, 8, 64);
        se += __shfl_xor(se, 16, 64);
        se += __shfl_xor(se, 32, 64);
        score_s[t] = e / se;
    }
    __syncthreads();

    // res[l=t] = sum_s score[s] * sigmoid(v[s,t])   -- thread-local
    float r = 0.f;
    #pragma unroll
    for (int s = 0; s < NS; ++s) {
        r = fmaf(score_s[s], sigmoidf_(acc_v[s]), r);
    }
    res[(b * NH + h) * NL + t] = r;
}

// ---------------------------------------------------------------------------
// Kernel 3: out[b] = sigmoid(res[b] @ O), plus origin passthrough.
// 4 batches per block to reuse O columns.
// ---------------------------------------------------------------------------
__global__ __launch_bounds__(256) void out_kernel(
        const float* __restrict__ x,
        const float* __restrict__ res,
        const float* __restrict__ O,
        float* __restrict__ out) {
    int b0 = blockIdx.x * 4;
    int t  = threadIdx.x;
    __shared__ float r_s[2048][4];     // [i][bb], 32KB
    #pragma unroll
    for (int bb = 0; bb < 4; ++bb) {
        const float* rr = res + (b0 + bb) * 2048;
        for (int i = t; i < 2048; i += 256) r_s[i][bb] = rr[i];
    }
    __syncthreads();
    float acc0 = 0.f, acc1 = 0.f, acc2 = 0.f, acc3 = 0.f;
    #pragma unroll 4
    for (int i = 0; i < 2048; ++i) {
        float o = O[i * 256 + t];      // coalesced, L2-resident (2MB)
        float4 rv = *(const float4*)(&r_s[i][0]);  // broadcast
        acc0 = fmaf(rv.x, o, acc0);
        acc1 = fmaf(rv.y, o, acc1);
        acc2 = fmaf(rv.z, o, acc2);
        acc3 = fmaf(rv.w, o, acc3);
    }
    float accs[4] = {acc0, acc1, acc2, acc3};
    #pragma unroll
    for (int bb = 0; bb < 4; ++bb) {
        out[(b0 + bb) * 512 + t]       = sigmoidf_(accs[bb]);
        out[(b0 + bb) * 512 + 256 + t] = x[(b0 + bb) * (NSEQ * ND) + t];  // origin
    }
}

// ---------------------------------------------------------------------------
extern "C" void kernel_launch(void* const* d_in, const int* in_sizes, int n_in,
                              void* d_out, int out_size, void* d_ws, size_t ws_size,
                              hipStream_t stream) {
    const float* x    = (const float*)d_in[0];
    const float* Wq   = (const float*)d_in[1];
    const float* Wk   = (const float*)d_in[2];
    const float* Wv   = (const float*)d_in[3];
    const float* W    = (const float*)d_in[4];
    const float* O    = (const float*)d_in[5];
    const float* P    = (const float*)d_in[6];
    const float* bias = (const float*)d_in[7];
    float* out = (float*)d_out;

    float* PK  = (float*)d_ws;                         // 8*64*256 f32 = 512 KB
    float* res = (float*)d_ws + NH * NS * NL;          // 2048*2048 f32 = 16 MB

    pk_kernel<<<NH * NS, 256, 0, stream>>>(P, Wk, PK);
    attn_kernel<<<NH * NB, 256, 0, stream>>>(x, Wq, Wk, Wv, W, bias, PK, res);
    out_kernel<<<NB / 4, 256, 0, stream>>>(x, res, O, out);
}

// Round 2
// 3822.145 us; speedup vs baseline: 2.0303x; 2.0303x over previous
//
#include <hip/hip_runtime.h>
#include <math.h>

#define NB   2048   // batch
#define NSEQ 65     // sequence incl. origin
#define ND   256    // IN_DIM
#define NH   8      // heads
#define NL   256    // L
#define NS   64     // walk length (S-1)

__device__ __forceinline__ float sigmoidf_(float x) { return 1.0f / (1.0f + __expf(-x)); }

// ---------------------------------------------------------------------------
// Kernel 1: PK[h][s][l] = sum_d P[s][d] * Wk[h][d][l]   (batch-independent)
// ---------------------------------------------------------------------------
__global__ __launch_bounds__(256) void pk_kernel(const float* __restrict__ P,
                                                 const float* __restrict__ Wk,
                                                 float* __restrict__ PK) {
    int h = blockIdx.x >> 6;
    int s = blockIdx.x & 63;
    int t = threadIdx.x;
    __shared__ float p_s[ND];
    p_s[t] = P[s * ND + t];
    __syncthreads();
    const float* wk = Wk + h * (ND * NL) + t;
    float acc = 0.f;
    #pragma unroll 8
    for (int d = 0; d < ND; ++d) acc = fmaf(p_s[d], wk[d * NL], acc);
    PK[(h * NS + s) * NL + t] = acc;
}

// ---------------------------------------------------------------------------
// Kernel 2: per (b,h). Thread tile: 16 s-rows x 4 l-cols.
//   t = lg + 64*sg;  lane lg owns l = lg*4..lg*4+3;  wave sg owns s = sg*16..+15
// Walk staged transposed in LDS [d][s] (row pad 68 floats, 16B-aligned rows):
//   - staging: thread writes float4 in s-direction -> bank-quad starts
//     (4d+s0)%32 cover all 32 banks per phase -> conflict-free
//   - inner reads: 4x ds_read_b128, identical addresses across the wave
//     (broadcast -> free)
// ---------------------------------------------------------------------------
__global__ __launch_bounds__(256, 2) void attn_kernel(
        const float* __restrict__ x,
        const float* __restrict__ Wq,
        const float* __restrict__ Wk,
        const float* __restrict__ Wv,
        const float* __restrict__ W,
        const float* __restrict__ bias,
        const float* __restrict__ PK,
        float* __restrict__ res) {
    int h = blockIdx.x >> 11;          // h-major: concurrent blocks share a head
    int b = blockIdx.x & 2047;
    int t = threadIdx.x;
    int lg = t & 63;                   // l-group (lane)
    int sg = t >> 6;                   // s-group (wave)

    __shared__ float walkT[128][68];   // [d-in-tile][s], pad 68: rows 272B (16B mult)
    __shared__ float origin_s[ND];
    __shared__ float score_s[NS];
    __shared__ float red[4][NL];

    const float* xb = x + b * (NSEQ * ND);
    origin_s[t] = xb[t];

    float4 acc_q[16], acc_v[16];
    #pragma unroll
    for (int i = 0; i < 16; ++i) {
        acc_q[i] = make_float4(0.f, 0.f, 0.f, 0.f);
        acc_v[i] = make_float4(0.f, 0.f, 0.f, 0.f);
    }
    float4 acc_k = make_float4(0.f, 0.f, 0.f, 0.f);

    const float* wq_p = Wq + h * (ND * NL) + lg * 4;
    const float* wk_p = Wk + h * (ND * NL) + lg * 4;
    const float* wv_p = Wv + h * (ND * NL) + lg * 4;

    for (int tile = 0; tile < 2; ++tile) {
        int d0 = tile * 128;
        __syncthreads();               // protect previous tile (and origin_s on tile 0)
        // stage walk tile transposed: (d, s-quad) pairs, coalesced global reads
        #pragma unroll
        for (int it = 0; it < 8; ++it) {
            int idx = t + it * 256;    // [0, 2048)
            int d   = idx & 127;
            int s0  = (idx >> 7) << 2; // 0,4,...,60
            const float* src = xb + (1 + s0) * ND + d0 + d;
            float4 f;
            f.x = src[0 * ND];
            f.y = src[1 * ND];
            f.z = src[2 * ND];
            f.w = src[3 * ND];
            *(float4*)(&walkT[d][s0]) = f;
        }
        __syncthreads();

        #pragma unroll 2
        for (int dd = 0; dd < 128; ++dd) {
            int d = d0 + dd;
            const float4 wq4 = *(const float4*)(wq_p + d * NL);
            const float4 wv4 = *(const float4*)(wv_p + d * NL);
            const float4 wk4 = *(const float4*)(wk_p + d * NL);
            float og = origin_s[d];
            acc_k.x = fmaf(og, wk4.x, acc_k.x);
            acc_k.y = fmaf(og, wk4.y, acc_k.y);
            acc_k.z = fmaf(og, wk4.z, acc_k.z);
            acc_k.w = fmaf(og, wk4.w, acc_k.w);
            const float4* wrow = (const float4*)(&walkT[dd][sg * 16]);
            float4 wr[4];
            wr[0] = wrow[0]; wr[1] = wrow[1]; wr[2] = wrow[2]; wr[3] = wrow[3];
            #pragma unroll
            for (int i4 = 0; i4 < 4; ++i4) {
                float4 w4 = wr[i4];
                float ws[4] = {w4.x, w4.y, w4.z, w4.w};
                #pragma unroll
                for (int c = 0; c < 4; ++c) {
                    int i = i4 * 4 + c;
                    float wv_ = ws[c];
                    acc_q[i].x = fmaf(wv_, wq4.x, acc_q[i].x);
                    acc_q[i].y = fmaf(wv_, wq4.y, acc_q[i].y);
                    acc_q[i].z = fmaf(wv_, wq4.z, acc_q[i].z);
                    acc_q[i].w = fmaf(wv_, wq4.w, acc_q[i].w);
                    acc_v[i].x = fmaf(wv_, wv4.x, acc_v[i].x);
                    acc_v[i].y = fmaf(wv_, wv4.y, acc_v[i].y);
                    acc_v[i].z = fmaf(wv_, wv4.z, acc_v[i].z);
                    acc_v[i].w = fmaf(wv_, wv4.w, acc_v[i].w);
                }
            }
        }
    }

    // --- edge + per-thread partial score over its 4 l-columns ---------------
    float bh = bias[h];
    const float4 w4h = *(const float4*)(W + h * NL + lg * 4);  // W is (H,L,1)
    float partial[16];
    #pragma unroll
    for (int i = 0; i < 16; ++i) {
        int s = sg * 16 + i;
        const float4 pk4 = *(const float4*)(PK + (h * NS + s) * NL + lg * 4);
        float qx = sigmoidf_(acc_q[i].x);
        float qy = sigmoidf_(acc_q[i].y);
        float qz = sigmoidf_(acc_q[i].z);
        float qw = sigmoidf_(acc_q[i].w);
        float kx = sigmoidf_(acc_k.x + pk4.x);
        float ky = sigmoidf_(acc_k.y + pk4.y);
        float kz = sigmoidf_(acc_k.z + pk4.z);
        float kw = sigmoidf_(acc_k.w + pk4.w);
        float p = (__cosf(kx * qx) + bh) * w4h.x;
        p = fmaf(__cosf(ky * qy) + bh, w4h.y, p);
        p = fmaf(__cosf(kz * qz) + bh, w4h.z, p);
        p = fmaf(__cosf(kw * qw) + bh, w4h.w, p);
        partial[i] = p;
    }
    // reduce over the 64 lanes (l-groups); wave sg owns s-rows sg*16..+15
    #pragma unroll
    for (int i = 0; i < 16; ++i) {
        float v = partial[i];
        v += __shfl_xor(v, 1, 64);
        v += __shfl_xor(v, 2, 64);
        v += __shfl_xor(v, 4, 64);
        v += __shfl_xor(v, 8, 64);
        v += __shfl_xor(v, 16, 64);
        v += __shfl_xor(v, 32, 64);
        partial[i] = v;
    }
    if (lg == 0) {
        #pragma unroll
        for (int i = 0; i < 16; ++i) score_s[sg * 16 + i] = partial[i];
    }
    __syncthreads();

    // --- softmax over the 64 s values (wave 0) ------------------------------
    if (t < 64) {
        float sc = score_s[t];
        float m = sc;
        m = fmaxf(m, __shfl_xor(m, 1, 64));
        m = fmaxf(m, __shfl_xor(m, 2, 64));
        m = fmaxf(m, __shfl_xor(m, 4, 64));
        m = fmaxf(m, __shfl_xor(m, 8, 64));
        m = fmaxf(m, __shfl_xor(m, 16, 64));
        m = fmaxf(m, __shfl_xor(m, 32, 64));
        float e = __expf(sc - m);
        float se = e;
        se += __shfl_xor(se, 1, 64);
        se += __shfl_xor(se, 2, 64);
        se += __shfl_xor(se, 4, 64);
        se += __shfl_xor(se, 8, 64);
        se += __shfl_xor(se, 16, 64);
        se += __shfl_xor(se, 32, 64);
        score_s[t] = e / se;
    }
    __syncthreads();

    // --- res partial over this wave's 16 s, then cross-wave sum -------------
    float4 r = make_float4(0.f, 0.f, 0.f, 0.f);
    #pragma unroll
    for (int i = 0; i < 16; ++i) {
        float p = score_s[sg * 16 + i];
        r.x = fmaf(p, sigmoidf_(acc_v[i].x), r.x);
        r.y = fmaf(p, sigmoidf_(acc_v[i].y), r.y);
        r.z = fmaf(p, sigmoidf_(acc_v[i].z), r.z);
        r.w = fmaf(p, sigmoidf_(acc_v[i].w), r.w);
    }
    *(float4*)(&red[sg][lg * 4]) = r;
    __syncthreads();
    float rv = red[0][t] + red[1][t] + red[2][t] + red[3][t];
    res[(b * NH + h) * NL + t] = rv;
}

// ---------------------------------------------------------------------------
// Kernel 3: out[b] = sigmoid(res[b] @ O), plus origin passthrough.
// ---------------------------------------------------------------------------
__global__ __launch_bounds__(256) void out_kernel(
        const float* __restrict__ x,
        const float* __restrict__ res,
        const float* __restrict__ O,
        float* __restrict__ out) {
    int b0 = blockIdx.x * 4;
    int t  = threadIdx.x;
    __shared__ float r_s[2048][4];     // [i][bb], 32KB
    #pragma unroll
    for (int bb = 0; bb < 4; ++bb) {
        const float* rr = res + (b0 + bb) * 2048;
        for (int i = t; i < 2048; i += 256) r_s[i][bb] = rr[i];
    }
    __syncthreads();
    float acc0 = 0.f, acc1 = 0.f, acc2 = 0.f, acc3 = 0.f;
    #pragma unroll 4
    for (int i = 0; i < 2048; ++i) {
        float o = O[i * 256 + t];      // coalesced, L2-resident (2MB)
        float4 rv = *(const float4*)(&r_s[i][0]);  // broadcast
        acc0 = fmaf(rv.x, o, acc0);
        acc1 = fmaf(rv.y, o, acc1);
        acc2 = fmaf(rv.z, o, acc2);
        acc3 = fmaf(rv.w, o, acc3);
    }
    float accs[4] = {acc0, acc1, acc2, acc3};
    #pragma unroll
    for (int bb = 0; bb < 4; ++bb) {
        out[(b0 + bb) * 512 + t]       = sigmoidf_(accs[bb]);
        out[(b0 + bb) * 512 + 256 + t] = x[(b0 + bb) * (NSEQ * ND) + t];  // origin
    }
}

// ---------------------------------------------------------------------------
extern "C" void kernel_launch(void* const* d_in, const int* in_sizes, int n_in,
                              void* d_out, int out_size, void* d_ws, size_t ws_size,
                              hipStream_t stream) {
    const float* x    = (const float*)d_in[0];
    const float* Wq   = (const float*)d_in[1];
    const float* Wk   = (const float*)d_in[2];
    const float* Wv   = (const float*)d_in[3];
    const float* W    = (const float*)d_in[4];
    const float* O    = (const float*)d_in[5];
    const float* P    = (const float*)d_in[6];
    const float* bias = (const float*)d_in[7];
    float* out = (float*)d_out;

    float* PK  = (float*)d_ws;                         // 8*64*256 f32 = 512 KB
    float* res = (float*)d_ws + NH * NS * NL;          // 2048*2048 f32 = 16 MB

    pk_kernel<<<NH * NS, 256, 0, stream>>>(P, Wk, PK);
    attn_kernel<<<NH * NB, 256, 0, stream>>>(x, Wq, Wk, Wv, W, bias, PK, res);
    out_kernel<<<NB / 4, 256, 0, stream>>>(x, res, O, out);
}

// Round 3
// 1642.214 us; speedup vs baseline: 4.7253x; 2.3274x over previous
//
#include <hip/hip_runtime.h>
#include <math.h>

#define NB   2048   // batch
#define NSEQ 65     // sequence incl. origin
#define ND   256    // IN_DIM (K)
#define NH   8      // heads
#define NL   256    // L
#define NS   64     // walk length (S-1)
#define APAD 264    // padded A-tile row (fp16 elems): 528B rows -> 8-phase LDS reads

typedef _Float16 f16;
typedef _Float16 f16x8 __attribute__((ext_vector_type(8)));
typedef float    f32x4 __attribute__((ext_vector_type(4)));

__device__ __forceinline__ float sigmoidf_(float x) { return 1.0f / (1.0f + __expf(-x)); }

// ---------------------------------------------------------------------------
// Prep A: weights Wq/Wv (H,K,N) f32  ->  wh[(h*2+qv)][n][k] f16 (k contiguous)
// ---------------------------------------------------------------------------
__global__ __launch_bounds__(256) void wh_kernel(const float* __restrict__ Wq,
                                                 const float* __restrict__ Wv,
                                                 f16* __restrict__ wh) {
    int hq = blockIdx.x >> 4;            // h*2+qv
    int h  = hq >> 1, qv = hq & 1;
    int n  = ((blockIdx.x & 15) << 4) + (threadIdx.x >> 4);
    int kc = (threadIdx.x & 15) << 4;
    const float* src = (qv ? Wv : Wq) + h * (ND * NL);
    f16x8 t0, t1;
    #pragma unroll
    for (int j = 0; j < 8; ++j) t0[j] = (f16)src[(kc + j) * NL + n];
    #pragma unroll
    for (int j = 0; j < 8; ++j) t1[j] = (f16)src[(kc + 8 + j) * NL + n];
    f16* dst = wh + ((size_t)(hq * 256 + n)) * 256 + kc;
    *(f16x8*)dst       = t0;             // coalesced 32B/thread
    *(f16x8*)(dst + 8) = t1;
}

// ---------------------------------------------------------------------------
// PK[h][s][l] = P[s]·Wk[h][:,l]   (batch-independent, fp32)
// ---------------------------------------------------------------------------
__global__ __launch_bounds__(256) void pk_kernel(const float* __restrict__ P,
                                                 const float* __restrict__ Wk,
                                                 float* __restrict__ PK) {
    int h = blockIdx.x >> 6;
    int s = blockIdx.x & 63;
    int t = threadIdx.x;
    __shared__ float p_s[ND];
    p_s[t] = P[s * ND + t];
    __syncthreads();
    const float* wk = Wk + h * (ND * NL) + t;
    float acc = 0.f;
    #pragma unroll 8
    for (int d = 0; d < ND; ++d) acc = fmaf(p_s[d], wk[d * NL], acc);
    PK[(h * NS + s) * NL + t] = acc;
}

// ---------------------------------------------------------------------------
// OK[h][b][l] = origin_b·Wk[h][:,l]   (fp32; 32 batches/block to reuse Wk)
// ---------------------------------------------------------------------------
__global__ __launch_bounds__(256) void ok_kernel(const float* __restrict__ x,
                                                 const float* __restrict__ Wk,
                                                 float* __restrict__ OK) {
    int h  = blockIdx.x >> 6;
    int b0 = (blockIdx.x & 63) << 5;
    int t  = threadIdx.x;
    __shared__ float or_s[32][ND];
    #pragma unroll 4
    for (int bb = 0; bb < 32; ++bb) or_s[bb][t] = x[(size_t)(b0 + bb) * (NSEQ * ND) + t];
    __syncthreads();
    float acc[32];
    #pragma unroll
    for (int bb = 0; bb < 32; ++bb) acc[bb] = 0.f;
    const float* wkp = Wk + h * (ND * NL) + t;
    for (int d = 0; d < ND; ++d) {
        float wk = wkp[d * NL];
        #pragma unroll
        for (int bb = 0; bb < 32; ++bb) acc[bb] = fmaf(or_s[bb][d], wk, acc[bb]);
    }
    #pragma unroll 4
    for (int bb = 0; bb < 32; ++bb) OK[((size_t)h * NB + b0 + bb) * NL + t] = acc[bb];
}

// ---------------------------------------------------------------------------
// Main fused kernel: block = (b,h), h-major grid.
//   GEMM: M=64 (s), N=512 (q:0..255 | v:256..511), K=256, fp16 MFMA 16x16x32.
//   Wave w owns n-chunk w*128..w*128+127 (waves 0,1 = q; 2,3 = v).
//   A (walk) converted f32->f16 into LDS once; B frags straight from L2.
//   Epilogue fused: edge/score/softmax/res.
// ---------------------------------------------------------------------------
__global__ __launch_bounds__(256, 2) void attn_mfma(
        const float* __restrict__ x,
        const f16*   __restrict__ wh,
        const float* __restrict__ W,
        const float* __restrict__ bias,
        const float* __restrict__ PK,
        const float* __restrict__ OK,
        float* __restrict__ res) {
    int h = blockIdx.x >> 11;
    int b = blockIdx.x & 2047;
    int t = threadIdx.x;
    int w    = t >> 6;
    int lane = t & 63;
    int c = lane & 15;                   // MFMA col (and A row m)
    int g = lane >> 4;                   // quad

    __shared__ f16 A[NS * APAD];         // 33792 B
    __shared__ float redp[2][NS];
    __shared__ float score_s[NS];

    const float* xb = x + (size_t)b * (NSEQ * ND);

    // --- stage A: walk rows -> f16, row-major padded to 264 ---------------
    #pragma unroll
    for (int it = 0; it < 16; ++it) {
        int idx4 = it * 256 + t;         // [0,4096)
        int s  = idx4 >> 6;
        int kq = idx4 & 63;
        float4 v = *(const float4*)(xb + (1 + s) * ND + kq * 4);
        f16* dst = &A[s * APAD + kq * 4];
        dst[0] = (f16)v.x; dst[1] = (f16)v.y; dst[2] = (f16)v.z; dst[3] = (f16)v.w;
    }
    __syncthreads();

    // --- K-loop: 256 MFMA per wave, no barriers ---------------------------
    f32x4 acc[4][8];
    #pragma unroll
    for (int mt = 0; mt < 4; ++mt)
        #pragma unroll
        for (int nt = 0; nt < 8; ++nt)
            acc[mt][nt] = (f32x4){0.f, 0.f, 0.f, 0.f};

    const f16* bbase = wh + ((size_t)(h * 512 + w * 128 + c)) * 256;
    #pragma unroll 2
    for (int kk = 0; kk < 8; ++kk) {
        int k0 = kk * 32 + g * 8;
        f16x8 af[4];
        #pragma unroll
        for (int mt = 0; mt < 4; ++mt)
            af[mt] = *(const f16x8*)(&A[(mt * 16 + c) * APAD + k0]);
        #pragma unroll
        for (int nt = 0; nt < 8; ++nt) {
            f16x8 bf = *(const f16x8*)(bbase + nt * 16 * 256 + k0);
            #pragma unroll
            for (int mt = 0; mt < 4; ++mt)
                acc[mt][nt] = __builtin_amdgcn_mfma_f32_16x16x32_f16(af[mt], bf, acc[mt][nt], 0, 0, 0);
        }
    }

    // --- epilogue ----------------------------------------------------------
    // C/D layout: col = lane&15 (=c), row = g*4 + r; s = mt*16 + g*4 + r.
    float bh = bias[h];
    if (w < 2) {                         // q waves: edge -> score partials
        float part[4][4];
        #pragma unroll
        for (int mt = 0; mt < 4; ++mt)
            #pragma unroll
            for (int r = 0; r < 4; ++r) part[mt][r] = 0.f;
        #pragma unroll
        for (int nt = 0; nt < 8; ++nt) {
            int l = w * 128 + nt * 16 + c;
            float wl  = W[h * NL + l];
            float okv = OK[((size_t)h * NB + b) * NL + l];
            #pragma unroll
            for (int mt = 0; mt < 4; ++mt) {
                #pragma unroll
                for (int r = 0; r < 4; ++r) {
                    int s = mt * 16 + g * 4 + r;
                    float pk = PK[(h * NS + s) * NL + l];
                    float qs = sigmoidf_(acc[mt][nt][r]);
                    float ks = sigmoidf_(okv + pk);
                    part[mt][r] = fmaf(__cosf(ks * qs) + bh, wl, part[mt][r]);
                }
            }
        }
        #pragma unroll
        for (int mt = 0; mt < 4; ++mt) {
            #pragma unroll
            for (int r = 0; r < 4; ++r) {
                float v = part[mt][r];
                v += __shfl_xor(v, 1, 64);
                v += __shfl_xor(v, 2, 64);
                v += __shfl_xor(v, 4, 64);
                v += __shfl_xor(v, 8, 64);
                if (c == 0) redp[w][mt * 16 + g * 4 + r] = v;
            }
        }
    } else {                             // v waves: sigmoid in place
        #pragma unroll
        for (int mt = 0; mt < 4; ++mt)
            #pragma unroll
            for (int nt = 0; nt < 8; ++nt)
                #pragma unroll
                for (int r = 0; r < 4; ++r)
                    acc[mt][nt][r] = sigmoidf_(acc[mt][nt][r]);
    }
    __syncthreads();

    if (t < 64) {                        // softmax over s (wave 0)
        float sc = redp[0][t] + redp[1][t];
        float m = sc;
        m = fmaxf(m, __shfl_xor(m, 1, 64));
        m = fmaxf(m, __shfl_xor(m, 2, 64));
        m = fmaxf(m, __shfl_xor(m, 4, 64));
        m = fmaxf(m, __shfl_xor(m, 8, 64));
        m = fmaxf(m, __shfl_xor(m, 16, 64));
        m = fmaxf(m, __shfl_xor(m, 32, 64));
        float e = __expf(sc - m);
        float se = e;
        se += __shfl_xor(se, 1, 64);
        se += __shfl_xor(se, 2, 64);
        se += __shfl_xor(se, 4, 64);
        se += __shfl_xor(se, 8, 64);
        se += __shfl_xor(se, 16, 64);
        se += __shfl_xor(se, 32, 64);
        score_s[t] = e / se;
    }
    __syncthreads();

    if (w >= 2) {                        // res[l] = sum_s p_s * sigv[s,l]
        float ps[4][4];
        #pragma unroll
        for (int mt = 0; mt < 4; ++mt)
            #pragma unroll
            for (int r = 0; r < 4; ++r)
                ps[mt][r] = score_s[mt * 16 + g * 4 + r];
        #pragma unroll
        for (int nt = 0; nt < 8; ++nt) {
            float v = 0.f;
            #pragma unroll
            for (int mt = 0; mt < 4; ++mt)
                #pragma unroll
                for (int r = 0; r < 4; ++r)
                    v = fmaf(ps[mt][r], acc[mt][nt][r], v);
            v += __shfl_xor(v, 16, 64);
            v += __shfl_xor(v, 32, 64);
            if (g == 0)
                res[((size_t)b * NH + h) * NL + (w - 2) * 128 + nt * 16 + c] = v;
        }
    }
}

// ---------------------------------------------------------------------------
// out[b] = sigmoid(res[b] @ O), plus origin passthrough.
// ---------------------------------------------------------------------------
__global__ __launch_bounds__(256) void out_kernel(
        const float* __restrict__ x,
        const float* __restrict__ res,
        const float* __restrict__ O,
        float* __restrict__ out) {
    int b0 = blockIdx.x * 4;
    int t  = threadIdx.x;
    __shared__ float r_s[2048][4];
    #pragma unroll
    for (int bb = 0; bb < 4; ++bb) {
        const float* rr = res + (size_t)(b0 + bb) * 2048;
        for (int i = t; i < 2048; i += 256) r_s[i][bb] = rr[i];
    }
    __syncthreads();
    float acc0 = 0.f, acc1 = 0.f, acc2 = 0.f, acc3 = 0.f;
    #pragma unroll 4
    for (int i = 0; i < 2048; ++i) {
        float o = O[i * 256 + t];
        float4 rv = *(const float4*)(&r_s[i][0]);
        acc0 = fmaf(rv.x, o, acc0);
        acc1 = fmaf(rv.y, o, acc1);
        acc2 = fmaf(rv.z, o, acc2);
        acc3 = fmaf(rv.w, o, acc3);
    }
    float accs[4] = {acc0, acc1, acc2, acc3};
    #pragma unroll
    for (int bb = 0; bb < 4; ++bb) {
        out[(size_t)(b0 + bb) * 512 + t]       = sigmoidf_(accs[bb]);
        out[(size_t)(b0 + bb) * 512 + 256 + t] = x[(size_t)(b0 + bb) * (NSEQ * ND) + t];
    }
}

// ---------------------------------------------------------------------------
extern "C" void kernel_launch(void* const* d_in, const int* in_sizes, int n_in,
                              void* d_out, int out_size, void* d_ws, size_t ws_size,
                              hipStream_t stream) {
    const float* x    = (const float*)d_in[0];
    const float* Wq   = (const float*)d_in[1];
    const float* Wk   = (const float*)d_in[2];
    const float* Wv   = (const float*)d_in[3];
    const float* W    = (const float*)d_in[4];
    const float* O    = (const float*)d_in[5];
    const float* P    = (const float*)d_in[6];
    const float* bias = (const float*)d_in[7];
    float* out = (float*)d_out;

    // workspace carve (bytes): wh 2MB | PK 512KB | OK 16MB | res 16MB  (~36MB)
    char* wsb = (char*)d_ws;
    f16*   wh  = (f16*)wsb;                                   // 2*8*256*256*2B
    float* PK  = (float*)(wsb + 2097152);
    float* OK  = (float*)(wsb + 2621440);
    float* res = (float*)(wsb + 19398656);

    wh_kernel<<<256, 256, 0, stream>>>(Wq, Wv, wh);
    pk_kernel<<<NH * NS, 256, 0, stream>>>(P, Wk, PK);
    ok_kernel<<<512, 256, 0, stream>>>(x, Wk, OK);
    attn_mfma<<<NH * NB, 256, 0, stream>>>(x, wh, W, bias, PK, OK, res);
    out_kernel<<<NB / 4, 256, 0, stream>>>(x, res, O, out);
}

// Round 4
// 1143.879 us; speedup vs baseline: 6.7839x; 1.4357x over previous
//
#include <hip/hip_runtime.h>
#include <math.h>

#define NB   2048   // batch
#define NSEQ 65     // sequence incl. origin
#define ND   256    // IN_DIM (K)
#define NH   8      // heads
#define NL   256    // L
#define NS   64     // walk length (S-1)
#define APAD 264    // padded A row (fp16 elems)

typedef _Float16 f16;
typedef _Float16 f16x8 __attribute__((ext_vector_type(8)));
typedef float    f32x4 __attribute__((ext_vector_type(4)));

__device__ __forceinline__ float sigmoidf_(float x) {
    return __builtin_amdgcn_rcpf(1.0f + __expf(-x));   // rcp: 1-ulp, fine vs 0.104 budget
}

// ---------------------------------------------------------------------------
// Prep: Wq/Wv (H,K,N) f32 -> wh[(h*2+qv)][n][k] f16 (k contiguous)
// ---------------------------------------------------------------------------
__global__ __launch_bounds__(256) void wh_kernel(const float* __restrict__ Wq,
                                                 const float* __restrict__ Wv,
                                                 f16* __restrict__ wh) {
    int hq = blockIdx.x >> 4;
    int h  = hq >> 1, qv = hq & 1;
    int n  = ((blockIdx.x & 15) << 4) + (threadIdx.x >> 4);
    int kc = (threadIdx.x & 15) << 4;
    const float* src = (qv ? Wv : Wq) + h * (ND * NL);
    f16x8 t0, t1;
    #pragma unroll
    for (int j = 0; j < 8; ++j) t0[j] = (f16)src[(kc + j) * NL + n];
    #pragma unroll
    for (int j = 0; j < 8; ++j) t1[j] = (f16)src[(kc + 8 + j) * NL + n];
    f16* dst = wh + ((size_t)(hq * 256 + n)) * 256 + kc;
    *(f16x8*)dst       = t0;
    *(f16x8*)(dst + 8) = t1;
}

// ---------------------------------------------------------------------------
// PKT[h][l][s] = P[s]·Wk[h][:,l]   (TRANSPOSED so epilogue reads float4 over s)
// ---------------------------------------------------------------------------
__global__ __launch_bounds__(256) void pkt_kernel(const float* __restrict__ P,
                                                  const float* __restrict__ Wk,
                                                  float* __restrict__ PKT) {
    int h = blockIdx.x >> 6;
    int s = blockIdx.x & 63;
    int t = threadIdx.x;
    __shared__ float p_s[ND];
    p_s[t] = P[s * ND + t];
    __syncthreads();
    const float* wk = Wk + h * (ND * NL) + t;
    float acc = 0.f;
    #pragma unroll 8
    for (int d = 0; d < ND; ++d) acc = fmaf(p_s[d], wk[d * NL], acc);
    PKT[((size_t)h * NL + t) * NS + s] = acc;
}

// ---------------------------------------------------------------------------
// OK[h][b][l] = origin_b·Wk[h][:,l]
// ---------------------------------------------------------------------------
__global__ __launch_bounds__(256) void ok_kernel(const float* __restrict__ x,
                                                 const float* __restrict__ Wk,
                                                 float* __restrict__ OK) {
    int h  = blockIdx.x >> 6;
    int b0 = (blockIdx.x & 63) << 5;
    int t  = threadIdx.x;
    __shared__ float or_s[32][ND];
    #pragma unroll 4
    for (int bb = 0; bb < 32; ++bb) or_s[bb][t] = x[(size_t)(b0 + bb) * (NSEQ * ND) + t];
    __syncthreads();
    float acc[32];
    #pragma unroll
    for (int bb = 0; bb < 32; ++bb) acc[bb] = 0.f;
    const float* wkp = Wk + h * (ND * NL) + t;
    for (int d = 0; d < ND; ++d) {
        float wk = wkp[d * NL];
        #pragma unroll
        for (int bb = 0; bb < 32; ++bb) acc[bb] = fmaf(or_s[bb][d], wk, acc[bb]);
    }
    #pragma unroll 4
    for (int bb = 0; bb < 32; ++bb) OK[((size_t)h * NB + b0 + bb) * NL + t] = acc[bb];
}

// ---------------------------------------------------------------------------
// Main fused kernel: block=(b,h). Every wave w owns q-cols w*64..+63 (nt 0-3)
// AND v-cols w*64..+63 (nt 4-7) -> balanced epilogue across all 4 waves.
// ---------------------------------------------------------------------------
__global__ __launch_bounds__(256, 2) void attn_mfma(
        const float* __restrict__ x,
        const f16*   __restrict__ wh,
        const float* __restrict__ W,
        const float* __restrict__ bias,
        const float* __restrict__ PKT,
        const float* __restrict__ OK,
        float* __restrict__ res) {
    int h = blockIdx.x >> 11;
    int b = blockIdx.x & 2047;
    int t = threadIdx.x;
    int w    = t >> 6;
    int lane = t & 63;
    int c = lane & 15;                   // MFMA col within 16 (and A row m)
    int g = lane >> 4;                   // quad

    __shared__ f16 A[NS * APAD];         // 33792 B
    __shared__ float redp[4][NS];
    __shared__ float score_s[NS];

    const float* xb = x + (size_t)b * (NSEQ * ND);

    // --- stage A: walk f32 -> f16, row-major padded -----------------------
    #pragma unroll
    for (int it = 0; it < 16; ++it) {
        int idx4 = it * 256 + t;         // [0,4096) float4 units
        int s  = idx4 >> 6;
        int kq = idx4 & 63;
        float4 v = *(const float4*)(xb + (1 + s) * ND + kq * 4);
        f16* dst = &A[s * APAD + kq * 4];
        dst[0] = (f16)v.x; dst[1] = (f16)v.y; dst[2] = (f16)v.z; dst[3] = (f16)v.w;
    }
    __syncthreads();

    // --- K-loop: 256 MFMA per wave, no barriers ---------------------------
    f32x4 acc_q[4][4], acc_v[4][4];
    #pragma unroll
    for (int mt = 0; mt < 4; ++mt)
        #pragma unroll
        for (int nt = 0; nt < 4; ++nt) {
            acc_q[mt][nt] = (f32x4){0.f, 0.f, 0.f, 0.f};
            acc_v[mt][nt] = (f32x4){0.f, 0.f, 0.f, 0.f};
        }

    const f16* bq = wh + ((size_t)((h * 2 + 0) * 256 + w * 64 + c)) * 256;
    const f16* bv = wh + ((size_t)((h * 2 + 1) * 256 + w * 64 + c)) * 256;
    #pragma unroll 2
    for (int kk = 0; kk < 8; ++kk) {
        int k0 = kk * 32 + g * 8;
        f16x8 af[4];
        #pragma unroll
        for (int mt = 0; mt < 4; ++mt)
            af[mt] = *(const f16x8*)(&A[(mt * 16 + c) * APAD + k0]);
        #pragma unroll
        for (int nt = 0; nt < 4; ++nt) {
            f16x8 bfq = *(const f16x8*)(bq + nt * 16 * 256 + k0);
            f16x8 bfv = *(const f16x8*)(bv + nt * 16 * 256 + k0);
            #pragma unroll
            for (int mt = 0; mt < 4; ++mt) {
                acc_q[mt][nt] = __builtin_amdgcn_mfma_f32_16x16x32_f16(af[mt], bfq, acc_q[mt][nt], 0, 0, 0);
                acc_v[mt][nt] = __builtin_amdgcn_mfma_f32_16x16x32_f16(af[mt], bfv, acc_v[mt][nt], 0, 0, 0);
            }
        }
    }

    // --- epilogue: C/D layout col=c, row s = mt*16 + g*4 + r --------------
    float bh = bias[h];

    // q half: edge -> per-wave score partials (64 l-cols per wave)
    float part[4][4];
    #pragma unroll
    for (int mt = 0; mt < 4; ++mt)
        #pragma unroll
        for (int r = 0; r < 4; ++r) part[mt][r] = 0.f;

    const float* Wlp  = W + h * NL + w * 64 + c;
    const float* OKp  = OK + ((size_t)h * NB + b) * NL + w * 64 + c;
    const float* PKTp = PKT + ((size_t)h * NL + w * 64 + c) * NS + g * 4;
    #pragma unroll
    for (int nt = 0; nt < 4; ++nt) {
        float wl  = Wlp[nt * 16];
        float okv = OKp[nt * 16];
        const float* pkcol = PKTp + (size_t)nt * 16 * NS;
        #pragma unroll
        for (int mt = 0; mt < 4; ++mt) {
            float4 pk4 = *(const float4*)(pkcol + mt * 16);   // s = mt*16+g*4 .. +3
            float pks[4] = {pk4.x, pk4.y, pk4.z, pk4.w};
            #pragma unroll
            for (int r = 0; r < 4; ++r) {
                float qs = sigmoidf_(acc_q[mt][nt][r]);
                float ks = sigmoidf_(okv + pks[r]);
                part[mt][r] = fmaf(__cosf(ks * qs) + bh, wl, part[mt][r]);
            }
        }
    }
    #pragma unroll
    for (int mt = 0; mt < 4; ++mt) {
        #pragma unroll
        for (int r = 0; r < 4; ++r) {
            float v = part[mt][r];
            v += __shfl_xor(v, 1, 64);
            v += __shfl_xor(v, 2, 64);
            v += __shfl_xor(v, 4, 64);
            v += __shfl_xor(v, 8, 64);
            if (c == 0) redp[w][mt * 16 + g * 4 + r] = v;
        }
    }
    __syncthreads();

    if (t < 64) {                        // softmax over s (wave 0)
        float sc = redp[0][t] + redp[1][t] + redp[2][t] + redp[3][t];
        float m = sc;
        m = fmaxf(m, __shfl_xor(m, 1, 64));
        m = fmaxf(m, __shfl_xor(m, 2, 64));
        m = fmaxf(m, __shfl_xor(m, 4, 64));
        m = fmaxf(m, __shfl_xor(m, 8, 64));
        m = fmaxf(m, __shfl_xor(m, 16, 64));
        m = fmaxf(m, __shfl_xor(m, 32, 64));
        float e = __expf(sc - m);
        float se = e;
        se += __shfl_xor(se, 1, 64);
        se += __shfl_xor(se, 2, 64);
        se += __shfl_xor(se, 4, 64);
        se += __shfl_xor(se, 8, 64);
        se += __shfl_xor(se, 16, 64);
        se += __shfl_xor(se, 32, 64);
        score_s[t] = e / se;
    }
    __syncthreads();

    // v half: res[l] = sum_s p_s * sigmoid(v[s,l]) for this wave's 64 cols
    float ps[4][4];
    #pragma unroll
    for (int mt = 0; mt < 4; ++mt)
        #pragma unroll
        for (int r = 0; r < 4; ++r)
            ps[mt][r] = score_s[mt * 16 + g * 4 + r];
    #pragma unroll
    for (int nt = 0; nt < 4; ++nt) {
        float v = 0.f;
        #pragma unroll
        for (int mt = 0; mt < 4; ++mt)
            #pragma unroll
            for (int r = 0; r < 4; ++r)
                v = fmaf(ps[mt][r], sigmoidf_(acc_v[mt][nt][r]), v);
        v += __shfl_xor(v, 16, 64);
        v += __shfl_xor(v, 32, 64);
        if (g == 0)
            res[((size_t)b * NH + h) * NL + w * 64 + nt * 16 + c] = v;
    }
}

// ---------------------------------------------------------------------------
// out[b] = sigmoid(res[b] @ O), plus origin passthrough.
// ---------------------------------------------------------------------------
__global__ __launch_bounds__(256) void out_kernel(
        const float* __restrict__ x,
        const float* __restrict__ res,
        const float* __restrict__ O,
        float* __restrict__ out) {
    int b0 = blockIdx.x * 4;
    int t  = threadIdx.x;
    __shared__ float r_s[2048][4];
    #pragma unroll
    for (int bb = 0; bb < 4; ++bb) {
        const float* rr = res + (size_t)(b0 + bb) * 2048;
        for (int i = t; i < 2048; i += 256) r_s[i][bb] = rr[i];
    }
    __syncthreads();
    float acc0 = 0.f, acc1 = 0.f, acc2 = 0.f, acc3 = 0.f;
    #pragma unroll 4
    for (int i = 0; i < 2048; ++i) {
        float o = O[i * 256 + t];
        float4 rv = *(const float4*)(&r_s[i][0]);
        acc0 = fmaf(rv.x, o, acc0);
        acc1 = fmaf(rv.y, o, acc1);
        acc2 = fmaf(rv.z, o, acc2);
        acc3 = fmaf(rv.w, o, acc3);
    }
    float accs[4] = {acc0, acc1, acc2, acc3};
    #pragma unroll
    for (int bb = 0; bb < 4; ++bb) {
        out[(size_t)(b0 + bb) * 512 + t]       = sigmoidf_(accs[bb]);
        out[(size_t)(b0 + bb) * 512 + 256 + t] = x[(size_t)(b0 + bb) * (NSEQ * ND) + t];
    }
}

// ---------------------------------------------------------------------------
extern "C" void kernel_launch(void* const* d_in, const int* in_sizes, int n_in,
                              void* d_out, int out_size, void* d_ws, size_t ws_size,
                              hipStream_t stream) {
    const float* x    = (const float*)d_in[0];
    const float* Wq   = (const float*)d_in[1];
    const float* Wk   = (const float*)d_in[2];
    const float* Wv   = (const float*)d_in[3];
    const float* W    = (const float*)d_in[4];
    const float* O    = (const float*)d_in[5];
    const float* P    = (const float*)d_in[6];
    const float* bias = (const float*)d_in[7];
    float* out = (float*)d_out;

    // workspace carve (bytes): wh 2MB | PKT 512KB | OK 16MB | res 16MB (~35MB)
    char* wsb = (char*)d_ws;
    f16*   wh  = (f16*)wsb;
    float* PKT = (float*)(wsb + 2097152);
    float* OK  = (float*)(wsb + 2621440);
    float* res = (float*)(wsb + 19398656);

    wh_kernel<<<256, 256, 0, stream>>>(Wq, Wv, wh);
    pkt_kernel<<<NH * NS, 256, 0, stream>>>(P, Wk, PKT);
    ok_kernel<<<512, 256, 0, stream>>>(x, Wk, OK);
    attn_mfma<<<NH * NB, 256, 0, stream>>>(x, wh, W, bias, PKT, OK, res);
    out_kernel<<<NB / 4, 256, 0, stream>>>(x, res, O, out);
}

// Round 5
// 1074.025 us; speedup vs baseline: 7.2251x; 1.0650x over previous
//
#include <hip/hip_runtime.h>
#include <math.h>

#define NB   2048   // batch
#define NSEQ 65     // sequence incl. origin
#define ND   256    // IN_DIM (K)
#define NH   8      // heads
#define NL   256    // L
#define NS   64     // walk length (S-1)
#define APAD 264    // padded A row (fp16 elems)

typedef _Float16 f16;
typedef _Float16 f16x4 __attribute__((ext_vector_type(4)));
typedef _Float16 f16x8 __attribute__((ext_vector_type(8)));
typedef float    f32x4 __attribute__((ext_vector_type(4)));

__device__ __forceinline__ float sigmoidf_(float x) {
    return __builtin_amdgcn_rcpf(1.0f + __expf(-x));
}

// ---------------------------------------------------------------------------
// Prep: Wq/Wv/Wk (H,K,N) f32 -> wh[(h*3+m)][n][k] f16 (k contiguous), m=q,v,k
// ---------------------------------------------------------------------------
__global__ __launch_bounds__(256) void wh_kernel(const float* __restrict__ Wq,
                                                 const float* __restrict__ Wv,
                                                 const float* __restrict__ Wk,
                                                 f16* __restrict__ wh) {
    int hm = blockIdx.x >> 4;            // h*3+m, 24 values
    int h  = hm / 3, m = hm % 3;
    int n  = ((blockIdx.x & 15) << 4) + (threadIdx.x >> 4);
    int kc = (threadIdx.x & 15) << 4;
    const float* src = (m == 0 ? Wq : (m == 1 ? Wv : Wk)) + h * (ND * NL);
    f16x8 t0, t1;
    #pragma unroll
    for (int j = 0; j < 8; ++j) t0[j] = (f16)src[(kc + j) * NL + n];
    #pragma unroll
    for (int j = 0; j < 8; ++j) t1[j] = (f16)src[(kc + 8 + j) * NL + n];
    f16* dst = wh + ((size_t)(hm * 256 + n)) * 256 + kc;
    *(f16x8*)dst       = t0;
    *(f16x8*)(dst + 8) = t1;
}

// ---------------------------------------------------------------------------
// Prep: O (2048,256) f32 -> OT[n][k] f16 (k contiguous)
// ---------------------------------------------------------------------------
__global__ __launch_bounds__(256) void ot_kernel(const float* __restrict__ O,
                                                 f16* __restrict__ OT) {
    int n = blockIdx.x;
    int t = threadIdx.x;
    f16x8 v;
    #pragma unroll
    for (int j = 0; j < 8; ++j) v[j] = (f16)O[(size_t)(t * 8 + j) * 256 + n];
    *(f16x8*)(OT + (size_t)n * 2048 + t * 8) = v;
}

// ---------------------------------------------------------------------------
// PKT[h][l][s] = P[s]·Wk[h][:,l]  (transposed: epilogue reads float4 over s)
// ---------------------------------------------------------------------------
__global__ __launch_bounds__(256) void pkt_kernel(const float* __restrict__ P,
                                                  const float* __restrict__ Wk,
                                                  float* __restrict__ PKT) {
    int h = blockIdx.x >> 6;
    int s = blockIdx.x & 63;
    int t = threadIdx.x;
    __shared__ float p_s[ND];
    p_s[t] = P[s * ND + t];
    __syncthreads();
    const float* wk = Wk + h * (ND * NL) + t;
    float acc = 0.f;
    #pragma unroll 8
    for (int d = 0; d < ND; ++d) acc = fmaf(p_s[d], wk[d * NL], acc);
    PKT[((size_t)h * NL + t) * NS + s] = acc;
}

// ---------------------------------------------------------------------------
// Main fused kernel, phase-split for occupancy:
//   phase 1: q-GEMM + k-GEMV (origin tile) -> 80 acc regs
//   q-epilogue: edge -> score partials (q/k accs die)
//   phase 2: v-GEMM reusing AGPRs -> softmax barrier after it -> res (f16)
// ---------------------------------------------------------------------------
__global__ __launch_bounds__(256, 3) void attn_mfma(
        const float* __restrict__ x,
        const f16*   __restrict__ wh,
        const float* __restrict__ W,
        const float* __restrict__ bias,
        const float* __restrict__ PKT,
        f16* __restrict__ res) {
    int b = blockIdx.x >> 3;             // b-major: 8 heads of a batch run close
    int h = blockIdx.x & 7;
    int t = threadIdx.x;
    int w    = t >> 6;
    int lane = t & 63;
    int c = lane & 15;
    int g = lane >> 4;

    __shared__ f16 A[NS * APAD];         // 33792 B walk tile
    __shared__ f16 A2[16 * APAD];        // 8448 B: row0=origin, rows1-15 zero
    __shared__ float redp[4][NS];
    __shared__ float score_s[NS];

    const float* xb = x + (size_t)b * (NSEQ * ND);

    // --- stage A (walk) -----------------------------------------------------
    #pragma unroll
    for (int it = 0; it < 16; ++it) {
        int idx4 = it * 256 + t;
        int s  = idx4 >> 6;
        int kq = idx4 & 63;
        float4 v = *(const float4*)(xb + (1 + s) * ND + kq * 4);
        f16* dst = &A[s * APAD + kq * 4];
        dst[0] = (f16)v.x; dst[1] = (f16)v.y; dst[2] = (f16)v.z; dst[3] = (f16)v.w;
    }
    // --- stage A2 (origin row + zeros) -------------------------------------
    for (int i = t; i < 16 * APAD / 4; i += 256)
        *(f16x4*)(&A2[i * 4]) = (f16x4){(f16)0.f, (f16)0.f, (f16)0.f, (f16)0.f};
    if (t < 64) {
        float4 v = *(const float4*)(xb + t * 4);
        *(f16x4*)(&A2[t * 4]) = (f16x4){(f16)v.x, (f16)v.y, (f16)v.z, (f16)v.w};
    }
    __syncthreads();

    const f16* bq = wh + ((size_t)((h * 3 + 0) * 256 + w * 64 + c)) * 256;
    const f16* bv = wh + ((size_t)((h * 3 + 1) * 256 + w * 64 + c)) * 256;
    const f16* bk = wh + ((size_t)((h * 3 + 2) * 256 + w * 64 + c)) * 256;

    // --- phase 1: q + k -----------------------------------------------------
    f32x4 acc_q[4][4], acc_k[4];
    #pragma unroll
    for (int mt = 0; mt < 4; ++mt)
        #pragma unroll
        for (int nt = 0; nt < 4; ++nt) acc_q[mt][nt] = (f32x4){0.f, 0.f, 0.f, 0.f};
    #pragma unroll
    for (int nt = 0; nt < 4; ++nt) acc_k[nt] = (f32x4){0.f, 0.f, 0.f, 0.f};

    #pragma unroll 2
    for (int kk = 0; kk < 8; ++kk) {
        int k0 = kk * 32 + g * 8;
        f16x8 af[4];
        #pragma unroll
        for (int mt = 0; mt < 4; ++mt)
            af[mt] = *(const f16x8*)(&A[(mt * 16 + c) * APAD + k0]);
        f16x8 af2 = *(const f16x8*)(&A2[c * APAD + k0]);
        #pragma unroll
        for (int nt = 0; nt < 4; ++nt) {
            f16x8 bfq = *(const f16x8*)(bq + nt * 16 * 256 + k0);
            f16x8 bfk = *(const f16x8*)(bk + nt * 16 * 256 + k0);
            acc_k[nt] = __builtin_amdgcn_mfma_f32_16x16x32_f16(af2, bfk, acc_k[nt], 0, 0, 0);
            #pragma unroll
            for (int mt = 0; mt < 4; ++mt)
                acc_q[mt][nt] = __builtin_amdgcn_mfma_f32_16x16x32_f16(af[mt], bfq, acc_q[mt][nt], 0, 0, 0);
        }
    }

    // --- q epilogue: edge -> per-wave score partials ------------------------
    float bh = bias[h];
    float part[4][4];
    #pragma unroll
    for (int mt = 0; mt < 4; ++mt)
        #pragma unroll
        for (int r = 0; r < 4; ++r) part[mt][r] = 0.f;

    const float* Wlp  = W + h * NL + w * 64 + c;
    const float* PKTp = PKT + ((size_t)h * NL + w * 64 + c) * NS + g * 4;
    #pragma unroll
    for (int nt = 0; nt < 4; ++nt) {
        float wl  = Wlp[nt * 16];
        float okv = __shfl(acc_k[nt][0], c, 64);   // D row0 lives at g=0,r=0
        const float* pkcol = PKTp + (size_t)nt * 16 * NS;
        #pragma unroll
        for (int mt = 0; mt < 4; ++mt) {
            float4 pk4 = *(const float4*)(pkcol + mt * 16);
            float pks[4] = {pk4.x, pk4.y, pk4.z, pk4.w};
            #pragma unroll
            for (int r = 0; r < 4; ++r) {
                float qs = sigmoidf_(acc_q[mt][nt][r]);
                float ks = sigmoidf_(okv + pks[r]);
                part[mt][r] = fmaf(__cosf(ks * qs) + bh, wl, part[mt][r]);
            }
        }
    }
    #pragma unroll
    for (int mt = 0; mt < 4; ++mt) {
        #pragma unroll
        for (int r = 0; r < 4; ++r) {
            float v = part[mt][r];
            v += __shfl_xor(v, 1, 64);
            v += __shfl_xor(v, 2, 64);
            v += __shfl_xor(v, 4, 64);
            v += __shfl_xor(v, 8, 64);
            if (c == 0) redp[w][mt * 16 + g * 4 + r] = v;
        }
    }

    // --- phase 2: v-GEMM (AGPRs reused; overlaps other waves' reductions) ---
    f32x4 acc_v[4][4];
    #pragma unroll
    for (int mt = 0; mt < 4; ++mt)
        #pragma unroll
        for (int nt = 0; nt < 4; ++nt) acc_v[mt][nt] = (f32x4){0.f, 0.f, 0.f, 0.f};
    #pragma unroll 2
    for (int kk = 0; kk < 8; ++kk) {
        int k0 = kk * 32 + g * 8;
        f16x8 af[4];
        #pragma unroll
        for (int mt = 0; mt < 4; ++mt)
            af[mt] = *(const f16x8*)(&A[(mt * 16 + c) * APAD + k0]);
        #pragma unroll
        for (int nt = 0; nt < 4; ++nt) {
            f16x8 bfv = *(const f16x8*)(bv + nt * 16 * 256 + k0);
            #pragma unroll
            for (int mt = 0; mt < 4; ++mt)
                acc_v[mt][nt] = __builtin_amdgcn_mfma_f32_16x16x32_f16(af[mt], bfv, acc_v[mt][nt], 0, 0, 0);
        }
    }
    __syncthreads();

    if (t < 64) {                        // softmax over s (wave 0)
        float sc = redp[0][t] + redp[1][t] + redp[2][t] + redp[3][t];
        float m = sc;
        m = fmaxf(m, __shfl_xor(m, 1, 64));
        m = fmaxf(m, __shfl_xor(m, 2, 64));
        m = fmaxf(m, __shfl_xor(m, 4, 64));
        m = fmaxf(m, __shfl_xor(m, 8, 64));
        m = fmaxf(m, __shfl_xor(m, 16, 64));
        m = fmaxf(m, __shfl_xor(m, 32, 64));
        float e = __expf(sc - m);
        float se = e;
        se += __shfl_xor(se, 1, 64);
        se += __shfl_xor(se, 2, 64);
        se += __shfl_xor(se, 4, 64);
        se += __shfl_xor(se, 8, 64);
        se += __shfl_xor(se, 16, 64);
        se += __shfl_xor(se, 32, 64);
        score_s[t] = e / se;
    }
    __syncthreads();

    // --- v epilogue: res f16 ------------------------------------------------
    float ps[4][4];
    #pragma unroll
    for (int mt = 0; mt < 4; ++mt)
        #pragma unroll
        for (int r = 0; r < 4; ++r)
            ps[mt][r] = score_s[mt * 16 + g * 4 + r];
    #pragma unroll
    for (int nt = 0; nt < 4; ++nt) {
        float v = 0.f;
        #pragma unroll
        for (int mt = 0; mt < 4; ++mt)
            #pragma unroll
            for (int r = 0; r < 4; ++r)
                v = fmaf(ps[mt][r], sigmoidf_(acc_v[mt][nt][r]), v);
        v += __shfl_xor(v, 16, 64);
        v += __shfl_xor(v, 32, 64);
        if (g == 0)
            res[(size_t)b * 2048 + h * NL + w * 64 + nt * 16 + c] = (f16)v;
    }
}

// ---------------------------------------------------------------------------
// out GEMM: out[b][0:256] = sigmoid(res[b] @ O)  (f16 MFMA, K=2048)
// block: 64 M-rows x 128 N-cols; nblk==1 blocks also copy origin passthrough.
// ---------------------------------------------------------------------------
__global__ __launch_bounds__(256) void out_gemm(
        const float* __restrict__ x,
        const f16*   __restrict__ res,
        const f16*   __restrict__ OT,
        float* __restrict__ out) {
    int mblk = blockIdx.x >> 1;
    int nblk = blockIdx.x & 1;
    int b0 = mblk * 64;
    int t  = threadIdx.x;
    int w    = t >> 6;
    int lane = t & 63;
    int c = lane & 15;
    int g = lane >> 4;

    __shared__ f16 Ao[64 * APAD];

    f32x4 acc[4][2];
    #pragma unroll
    for (int mt = 0; mt < 4; ++mt)
        #pragma unroll
        for (int nt = 0; nt < 2; ++nt) acc[mt][nt] = (f32x4){0.f, 0.f, 0.f, 0.f};

    for (int chunk = 0; chunk < 8; ++chunk) {
        int kbase = chunk * 256;
        __syncthreads();
        #pragma unroll
        for (int it = 0; it < 8; ++it) {
            int id  = it * 256 + t;
            int row = id >> 5;
            int kc  = (id & 31) << 3;
            *(f16x8*)(&Ao[row * APAD + kc]) =
                *(const f16x8*)(res + (size_t)(b0 + row) * 2048 + kbase + kc);
        }
        __syncthreads();
        #pragma unroll
        for (int kk = 0; kk < 8; ++kk) {
            int k0 = kk * 32 + g * 8;
            f16x8 af[4];
            #pragma unroll
            for (int mt = 0; mt < 4; ++mt)
                af[mt] = *(const f16x8*)(&Ao[(mt * 16 + c) * APAD + k0]);
            #pragma unroll
            for (int nt = 0; nt < 2; ++nt) {
                f16x8 bf = *(const f16x8*)(OT + (size_t)(nblk * 128 + w * 32 + nt * 16 + c) * 2048 + kbase + k0);
                #pragma unroll
                for (int mt = 0; mt < 4; ++mt)
                    acc[mt][nt] = __builtin_amdgcn_mfma_f32_16x16x32_f16(af[mt], bf, acc[mt][nt], 0, 0, 0);
            }
        }
    }
    #pragma unroll
    for (int mt = 0; mt < 4; ++mt)
        #pragma unroll
        for (int nt = 0; nt < 2; ++nt)
            #pragma unroll
            for (int r = 0; r < 4; ++r) {
                int row = mt * 16 + g * 4 + r;
                int col = nblk * 128 + w * 32 + nt * 16 + c;
                out[(size_t)(b0 + row) * 512 + col] = sigmoidf_(acc[mt][nt][r]);
            }
    if (nblk == 1) {                     // origin passthrough for these 64 rows
        for (int r2 = 0; r2 < 64; ++r2)
            out[(size_t)(b0 + r2) * 512 + 256 + t] = x[(size_t)(b0 + r2) * (NSEQ * ND) + t];
    }
}

// ---------------------------------------------------------------------------
extern "C" void kernel_launch(void* const* d_in, const int* in_sizes, int n_in,
                              void* d_out, int out_size, void* d_ws, size_t ws_size,
                              hipStream_t stream) {
    const float* x    = (const float*)d_in[0];
    const float* Wq   = (const float*)d_in[1];
    const float* Wk   = (const float*)d_in[2];
    const float* Wv   = (const float*)d_in[3];
    const float* W    = (const float*)d_in[4];
    const float* O    = (const float*)d_in[5];
    const float* P    = (const float*)d_in[6];
    const float* bias = (const float*)d_in[7];
    float* out = (float*)d_out;

    // ws carve: wh 3MB | OT 1MB | PKT 512KB | res 8MB
    char* wsb = (char*)d_ws;
    f16*   wh  = (f16*)wsb;                       // 3*8*256*256 f16 = 3145728 B
    f16*   OT  = (f16*)(wsb + 3145728);           // 256*2048 f16   = 1048576 B
    float* PKT = (float*)(wsb + 4194304);         // 8*256*64 f32   = 524288 B
    f16*   res = (f16*)(wsb + 4718592);           // 2048*2048 f16  = 8388608 B

    wh_kernel<<<384, 256, 0, stream>>>(Wq, Wv, Wk, wh);
    ot_kernel<<<256, 256, 0, stream>>>(O, OT);
    pkt_kernel<<<NH * NS, 256, 0, stream>>>(P, Wk, PKT);
    attn_mfma<<<NB * NH, 256, 0, stream>>>(x, wh, W, bias, PKT, res);
    out_gemm<<<64, 256, 0, stream>>>(x, res, OT, out);
}

// Round 6
// 1048.017 us; speedup vs baseline: 7.4044x; 1.0248x over previous
//
#include <hip/hip_runtime.h>
#include <math.h>

#define NB   2048   // batch
#define NSEQ 65     // sequence incl. origin
#define ND   256    // IN_DIM (K)
#define NH   8      // heads
#define NL   256    // L
#define NS   64     // walk length (S-1)
#define APAD 264    // padded A row (fp16 elems)

typedef _Float16 f16;
typedef _Float16 f16x4 __attribute__((ext_vector_type(4)));
typedef _Float16 f16x8 __attribute__((ext_vector_type(8)));
typedef float    f32x4 __attribute__((ext_vector_type(4)));

__device__ __forceinline__ float sigmoidf_(float x) {
    return __builtin_amdgcn_rcpf(1.0f + __expf(-x));
}

// ---------------------------------------------------------------------------
// Prep: Wq/Wv/Wk (H,K,N) f32 -> wh[(h*3+m)][n][k] f16 (k contiguous), m=q,v,k
// ---------------------------------------------------------------------------
__global__ __launch_bounds__(256) void wh_kernel(const float* __restrict__ Wq,
                                                 const float* __restrict__ Wv,
                                                 const float* __restrict__ Wk,
                                                 f16* __restrict__ wh) {
    int hm = blockIdx.x >> 4;            // h*3+m, 24 values
    int h  = hm / 3, m = hm % 3;
    int n  = ((blockIdx.x & 15) << 4) + (threadIdx.x >> 4);
    int kc = (threadIdx.x & 15) << 4;
    const float* src = (m == 0 ? Wq : (m == 1 ? Wv : Wk)) + h * (ND * NL);
    f16x8 t0, t1;
    #pragma unroll
    for (int j = 0; j < 8; ++j) t0[j] = (f16)src[(kc + j) * NL + n];
    #pragma unroll
    for (int j = 0; j < 8; ++j) t1[j] = (f16)src[(kc + 8 + j) * NL + n];
    f16* dst = wh + ((size_t)(hm * 256 + n)) * 256 + kc;
    *(f16x8*)dst       = t0;
    *(f16x8*)(dst + 8) = t1;
}

// ---------------------------------------------------------------------------
// Prep: O (2048,256) f32 -> OT[n][k] f16 (k contiguous)
// ---------------------------------------------------------------------------
__global__ __launch_bounds__(256) void ot_kernel(const float* __restrict__ O,
                                                 f16* __restrict__ OT) {
    int n = blockIdx.x;
    int t = threadIdx.x;
    f16x8 v;
    #pragma unroll
    for (int j = 0; j < 8; ++j) v[j] = (f16)O[(size_t)(t * 8 + j) * 256 + n];
    *(f16x8*)(OT + (size_t)n * 2048 + t * 8) = v;
}

// ---------------------------------------------------------------------------
// PKT[h][l][s] = P[s]·Wk[h][:,l]  (transposed: epilogue reads float4 over s)
// ---------------------------------------------------------------------------
__global__ __launch_bounds__(256) void pkt_kernel(const float* __restrict__ P,
                                                  const float* __restrict__ Wk,
                                                  float* __restrict__ PKT) {
    int h = blockIdx.x >> 6;
    int s = blockIdx.x & 63;
    int t = threadIdx.x;
    __shared__ float p_s[ND];
    p_s[t] = P[s * ND + t];
    __syncthreads();
    const float* wk = Wk + h * (ND * NL) + t;
    float acc = 0.f;
    #pragma unroll 8
    for (int d = 0; d < ND; ++d) acc = fmaf(p_s[d], wk[d * NL], acc);
    PKT[((size_t)h * NL + t) * NS + s] = acc;
}

// ---------------------------------------------------------------------------
// Main fused kernel: ONE BLOCK PER BATCH, 8 heads looped over one A-tile.
//   per head: phase1 q+k GEMM -> q-epilogue (redp) -> phase2 v-GEMM
//             -> barrier -> softmax -> barrier -> v-epilogue (res f16)
// ---------------------------------------------------------------------------
__global__ __launch_bounds__(256, 3) void attn_mfma(
        const float* __restrict__ x,
        const f16*   __restrict__ wh,
        const float* __restrict__ W,
        const float* __restrict__ bias,
        const float* __restrict__ PKT,
        f16* __restrict__ res) {
    int b = blockIdx.x;
    int t = threadIdx.x;
    int w    = t >> 6;
    int lane = t & 63;
    int c = lane & 15;
    int g = lane >> 4;

    __shared__ f16 A[NS * APAD];         // 33792 B walk tile (shared by 8 heads)
    __shared__ f16 A2[16 * APAD];        // 8448 B: row0=origin, rows1-15 zero
    __shared__ float redp[4][NS];
    __shared__ float score_s[NS];

    const float* xb = x + (size_t)b * (NSEQ * ND);

    // --- stage A (walk) once ----------------------------------------------
    #pragma unroll
    for (int it = 0; it < 16; ++it) {
        int idx4 = it * 256 + t;
        int s  = idx4 >> 6;
        int kq = idx4 & 63;
        float4 v = *(const float4*)(xb + (1 + s) * ND + kq * 4);
        f16* dst = &A[s * APAD + kq * 4];
        dst[0] = (f16)v.x; dst[1] = (f16)v.y; dst[2] = (f16)v.z; dst[3] = (f16)v.w;
    }
    // --- stage A2 (origin row + zeros) ------------------------------------
    for (int i = t; i < 16 * APAD / 4; i += 256)
        *(f16x4*)(&A2[i * 4]) = (f16x4){(f16)0.f, (f16)0.f, (f16)0.f, (f16)0.f};
    if (t < 64) {
        float4 v = *(const float4*)(xb + t * 4);
        *(f16x4*)(&A2[t * 4]) = (f16x4){(f16)v.x, (f16)v.y, (f16)v.z, (f16)v.w};
    }
    __syncthreads();

    for (int h = 0; h < NH; ++h) {
        const f16* bq = wh + ((size_t)((h * 3 + 0) * 256 + w * 64 + c)) * 256;
        const f16* bv = wh + ((size_t)((h * 3 + 1) * 256 + w * 64 + c)) * 256;
        const f16* bk = wh + ((size_t)((h * 3 + 2) * 256 + w * 64 + c)) * 256;

        // --- phase 1: q + k ------------------------------------------------
        f32x4 acc_q[4][4], acc_k[4];
        #pragma unroll
        for (int mt = 0; mt < 4; ++mt)
            #pragma unroll
            for (int nt = 0; nt < 4; ++nt) acc_q[mt][nt] = (f32x4){0.f, 0.f, 0.f, 0.f};
        #pragma unroll
        for (int nt = 0; nt < 4; ++nt) acc_k[nt] = (f32x4){0.f, 0.f, 0.f, 0.f};

        #pragma unroll 2
        for (int kk = 0; kk < 8; ++kk) {
            int k0 = kk * 32 + g * 8;
            f16x8 af[4];
            #pragma unroll
            for (int mt = 0; mt < 4; ++mt)
                af[mt] = *(const f16x8*)(&A[(mt * 16 + c) * APAD + k0]);
            f16x8 af2 = *(const f16x8*)(&A2[c * APAD + k0]);
            #pragma unroll
            for (int nt = 0; nt < 4; ++nt) {
                f16x8 bfq = *(const f16x8*)(bq + nt * 16 * 256 + k0);
                f16x8 bfk = *(const f16x8*)(bk + nt * 16 * 256 + k0);
                acc_k[nt] = __builtin_amdgcn_mfma_f32_16x16x32_f16(af2, bfk, acc_k[nt], 0, 0, 0);
                #pragma unroll
                for (int mt = 0; mt < 4; ++mt)
                    acc_q[mt][nt] = __builtin_amdgcn_mfma_f32_16x16x32_f16(af[mt], bfq, acc_q[mt][nt], 0, 0, 0);
            }
        }

        // --- q epilogue: edge -> per-wave score partials -------------------
        float bh = bias[h];
        float part[4][4];
        #pragma unroll
        for (int mt = 0; mt < 4; ++mt)
            #pragma unroll
            for (int r = 0; r < 4; ++r) part[mt][r] = 0.f;

        const float* Wlp  = W + h * NL + w * 64 + c;
        const float* PKTp = PKT + ((size_t)h * NL + w * 64 + c) * NS + g * 4;
        #pragma unroll
        for (int nt = 0; nt < 4; ++nt) {
            float wl  = Wlp[nt * 16];
            float okv = __shfl(acc_k[nt][0], c, 64);   // D row0 lives at g=0,r=0
            const float* pkcol = PKTp + (size_t)nt * 16 * NS;
            #pragma unroll
            for (int mt = 0; mt < 4; ++mt) {
                float4 pk4 = *(const float4*)(pkcol + mt * 16);
                float pks[4] = {pk4.x, pk4.y, pk4.z, pk4.w};
                #pragma unroll
                for (int r = 0; r < 4; ++r) {
                    float qs = sigmoidf_(acc_q[mt][nt][r]);
                    float ks = sigmoidf_(okv + pks[r]);
                    part[mt][r] = fmaf(__cosf(ks * qs) + bh, wl, part[mt][r]);
                }
            }
        }
        #pragma unroll
        for (int mt = 0; mt < 4; ++mt) {
            #pragma unroll
            for (int r = 0; r < 4; ++r) {
                float v = part[mt][r];
                v += __shfl_xor(v, 1, 64);
                v += __shfl_xor(v, 2, 64);
                v += __shfl_xor(v, 4, 64);
                v += __shfl_xor(v, 8, 64);
                if (c == 0) redp[w][mt * 16 + g * 4 + r] = v;
            }
        }

        // --- phase 2: v-GEMM (AGPRs reused) --------------------------------
        f32x4 acc_v[4][4];
        #pragma unroll
        for (int mt = 0; mt < 4; ++mt)
            #pragma unroll
            for (int nt = 0; nt < 4; ++nt) acc_v[mt][nt] = (f32x4){0.f, 0.f, 0.f, 0.f};
        #pragma unroll 2
        for (int kk = 0; kk < 8; ++kk) {
            int k0 = kk * 32 + g * 8;
            f16x8 af[4];
            #pragma unroll
            for (int mt = 0; mt < 4; ++mt)
                af[mt] = *(const f16x8*)(&A[(mt * 16 + c) * APAD + k0]);
            #pragma unroll
            for (int nt = 0; nt < 4; ++nt) {
                f16x8 bfv = *(const f16x8*)(bv + nt * 16 * 256 + k0);
                #pragma unroll
                for (int mt = 0; mt < 4; ++mt)
                    acc_v[mt][nt] = __builtin_amdgcn_mfma_f32_16x16x32_f16(af[mt], bfv, acc_v[mt][nt], 0, 0, 0);
            }
        }
        __syncthreads();                  // redp ready; head h-1's score_s consumed

        if (t < 64) {                     // softmax over s (wave 0)
            float sc = redp[0][t] + redp[1][t] + redp[2][t] + redp[3][t];
            float m = sc;
            m = fmaxf(m, __shfl_xor(m, 1, 64));
            m = fmaxf(m, __shfl_xor(m, 2, 64));
            m = fmaxf(m, __shfl_xor(m, 4, 64));
            m = fmaxf(m, __shfl_xor(m, 8, 64));
            m = fmaxf(m, __shfl_xor(m, 16, 64));
            m = fmaxf(m, __shfl_xor(m, 32, 64));
            float e = __expf(sc - m);
            float se = e;
            se += __shfl_xor(se, 1, 64);
            se += __shfl_xor(se, 2, 64);
            se += __shfl_xor(se, 4, 64);
            se += __shfl_xor(se, 8, 64);
            se += __shfl_xor(se, 16, 64);
            se += __shfl_xor(se, 32, 64);
            score_s[t] = e / se;
        }
        __syncthreads();

        // --- v epilogue: res f16 -------------------------------------------
        float ps[4][4];
        #pragma unroll
        for (int mt = 0; mt < 4; ++mt)
            #pragma unroll
            for (int r = 0; r < 4; ++r)
                ps[mt][r] = score_s[mt * 16 + g * 4 + r];
        #pragma unroll
        for (int nt = 0; nt < 4; ++nt) {
            float v = 0.f;
            #pragma unroll
            for (int mt = 0; mt < 4; ++mt)
                #pragma unroll
                for (int r = 0; r < 4; ++r)
                    v = fmaf(ps[mt][r], sigmoidf_(acc_v[mt][nt][r]), v);
            v += __shfl_xor(v, 16, 64);
            v += __shfl_xor(v, 32, 64);
            if (g == 0)
                res[(size_t)b * 2048 + h * NL + w * 64 + nt * 16 + c] = (f16)v;
        }
    }
}

// ---------------------------------------------------------------------------
// out GEMM: out[b][0:256] = sigmoid(res[b] @ O)  (f16 MFMA, K=2048)
// ---------------------------------------------------------------------------
__global__ __launch_bounds__(256) void out_gemm(
        const float* __restrict__ x,
        const f16*   __restrict__ res,
        const f16*   __restrict__ OT,
        float* __restrict__ out) {
    int mblk = blockIdx.x >> 1;
    int nblk = blockIdx.x & 1;
    int b0 = mblk * 64;
    int t  = threadIdx.x;
    int w    = t >> 6;
    int lane = t & 63;
    int c = lane & 15;
    int g = lane >> 4;

    __shared__ f16 Ao[64 * APAD];

    f32x4 acc[4][2];
    #pragma unroll
    for (int mt = 0; mt < 4; ++mt)
        #pragma unroll
        for (int nt = 0; nt < 2; ++nt) acc[mt][nt] = (f32x4){0.f, 0.f, 0.f, 0.f};

    for (int chunk = 0; chunk < 8; ++chunk) {
        int kbase = chunk * 256;
        __syncthreads();
        #pragma unroll
        for (int it = 0; it < 8; ++it) {
            int id  = it * 256 + t;
            int row = id >> 5;
            int kc  = (id & 31) << 3;
            *(f16x8*)(&Ao[row * APAD + kc]) =
                *(const f16x8*)(res + (size_t)(b0 + row) * 2048 + kbase + kc);
        }
        __syncthreads();
        #pragma unroll
        for (int kk = 0; kk < 8; ++kk) {
            int k0 = kk * 32 + g * 8;
            f16x8 af[4];
            #pragma unroll
            for (int mt = 0; mt < 4; ++mt)
                af[mt] = *(const f16x8*)(&Ao[(mt * 16 + c) * APAD + k0]);
            #pragma unroll
            for (int nt = 0; nt < 2; ++nt) {
                f16x8 bf = *(const f16x8*)(OT + (size_t)(nblk * 128 + w * 32 + nt * 16 + c) * 2048 + kbase + k0);
                #pragma unroll
                for (int mt = 0; mt < 4; ++mt)
                    acc[mt][nt] = __builtin_amdgcn_mfma_f32_16x16x32_f16(af[mt], bf, acc[mt][nt], 0, 0, 0);
            }
        }
    }
    #pragma unroll
    for (int mt = 0; mt < 4; ++mt)
        #pragma unroll
        for (int nt = 0; nt < 2; ++nt)
            #pragma unroll
            for (int r = 0; r < 4; ++r) {
                int row = mt * 16 + g * 4 + r;
                int col = nblk * 128 + w * 32 + nt * 16 + c;
                out[(size_t)(b0 + row) * 512 + col] = sigmoidf_(acc[mt][nt][r]);
            }
    if (nblk == 1) {                     // origin passthrough for these 64 rows
        for (int r2 = 0; r2 < 64; ++r2)
            out[(size_t)(b0 + r2) * 512 + 256 + t] = x[(size_t)(b0 + r2) * (NSEQ * ND) + t];
    }
}

// ---------------------------------------------------------------------------
extern "C" void kernel_launch(void* const* d_in, const int* in_sizes, int n_in,
                              void* d_out, int out_size, void* d_ws, size_t ws_size,
                              hipStream_t stream) {
    const float* x    = (const float*)d_in[0];
    const float* Wq   = (const float*)d_in[1];
    const float* Wk   = (const float*)d_in[2];
    const float* Wv   = (const float*)d_in[3];
    const float* W    = (const float*)d_in[4];
    const float* O    = (const float*)d_in[5];
    const float* P    = (const float*)d_in[6];
    const float* bias = (const float*)d_in[7];
    float* out = (float*)d_out;

    // ws carve: wh 3MB | OT 1MB | PKT 512KB | res 8MB
    char* wsb = (char*)d_ws;
    f16*   wh  = (f16*)wsb;                       // 3*8*256*256 f16 = 3145728 B
    f16*   OT  = (f16*)(wsb + 3145728);           // 256*2048 f16   = 1048576 B
    float* PKT = (float*)(wsb + 4194304);         // 8*256*64 f32   = 524288 B
    f16*   res = (f16*)(wsb + 4718592);           // 2048*2048 f16  = 8388608 B

    wh_kernel<<<384, 256, 0, stream>>>(Wq, Wv, Wk, wh);
    ot_kernel<<<256, 256, 0, stream>>>(O, OT);
    pkt_kernel<<<NH * NS, 256, 0, stream>>>(P, Wk, PKT);
    attn_mfma<<<NB, 256, 0, stream>>>(x, wh, W, bias, PKT, res);
    out_gemm<<<64, 256, 0, stream>>>(x, res, OT, out);
}

// Round 7
// 840.513 us; speedup vs baseline: 9.2324x; 1.2469x over previous
//
#include <hip/hip_runtime.h>
#include <math.h>

#define NB   2048   // batch
#define NSEQ 65     // sequence incl. origin
#define ND   256    // IN_DIM (K)
#define NH   8      // heads
#define NL   256    // L
#define NS   64     // walk length (S-1)
#define APAD 264    // padded A row (fp16 elems)

typedef _Float16 f16;
typedef _Float16 f16x4 __attribute__((ext_vector_type(4)));
typedef _Float16 f16x8 __attribute__((ext_vector_type(8)));
typedef float    f32x4 __attribute__((ext_vector_type(4)));

__device__ __forceinline__ float sigmoidf_(float x) {
    return __builtin_amdgcn_rcpf(1.0f + __expf(-x));
}

// ---------------------------------------------------------------------------
// Prep: Wq/Wv/Wk (H,K,N) f32 -> wh[(h*3+m)][n][k] f16 (k contiguous), m=q,v,k
// ---------------------------------------------------------------------------
__global__ __launch_bounds__(256) void wh_kernel(const float* __restrict__ Wq,
                                                 const float* __restrict__ Wv,
                                                 const float* __restrict__ Wk,
                                                 f16* __restrict__ wh) {
    int hm = blockIdx.x >> 4;            // h*3+m, 24 values
    int h  = hm / 3, m = hm % 3;
    int n  = ((blockIdx.x & 15) << 4) + (threadIdx.x >> 4);
    int kc = (threadIdx.x & 15) << 4;
    const float* src = (m == 0 ? Wq : (m == 1 ? Wv : Wk)) + h * (ND * NL);
    f16x8 t0, t1;
    #pragma unroll
    for (int j = 0; j < 8; ++j) t0[j] = (f16)src[(kc + j) * NL + n];
    #pragma unroll
    for (int j = 0; j < 8; ++j) t1[j] = (f16)src[(kc + 8 + j) * NL + n];
    f16* dst = wh + ((size_t)(hm * 256 + n)) * 256 + kc;
    *(f16x8*)dst       = t0;
    *(f16x8*)(dst + 8) = t1;
}

// ---------------------------------------------------------------------------
// Prep: O (2048,256) f32 -> OT[n][k] f16 (k contiguous)
// ---------------------------------------------------------------------------
__global__ __launch_bounds__(256) void ot_kernel(const float* __restrict__ O,
                                                 f16* __restrict__ OT) {
    int n = blockIdx.x;
    int t = threadIdx.x;
    f16x8 v;
    #pragma unroll
    for (int j = 0; j < 8; ++j) v[j] = (f16)O[(size_t)(t * 8 + j) * 256 + n];
    *(f16x8*)(OT + (size_t)n * 2048 + t * 8) = v;
}

// ---------------------------------------------------------------------------
// PKT[h][l][s] = P[s]·Wk[h][:,l]  (transposed: epilogue reads float4 over s)
// ---------------------------------------------------------------------------
__global__ __launch_bounds__(256) void pkt_kernel(const float* __restrict__ P,
                                                  const float* __restrict__ Wk,
                                                  float* __restrict__ PKT) {
    int h = blockIdx.x >> 6;
    int s = blockIdx.x & 63;
    int t = threadIdx.x;
    __shared__ float p_s[ND];
    p_s[t] = P[s * ND + t];
    __syncthreads();
    const float* wk = Wk + h * (ND * NL) + t;
    float acc = 0.f;
    #pragma unroll 8
    for (int d = 0; d < ND; ++d) acc = fmaf(p_s[d], wk[d * NL], acc);
    PKT[((size_t)h * NL + t) * NS + s] = acc;
}

// ---------------------------------------------------------------------------
// OK[h][b][l] = origin_b · Wk[h][:,l]  as f16 MFMA GEMM (M=2048,N=2048,K=256)
// block: 64 b-rows x 128 n-cols (one head half)
// ---------------------------------------------------------------------------
__global__ __launch_bounds__(256) void ok_gemm(const float* __restrict__ x,
                                               const f16*   __restrict__ wh,
                                               float* __restrict__ OK) {
    int mblk = blockIdx.x >> 4;          // 32
    int nblk = blockIdx.x & 15;          // 16
    int b0 = mblk * 64;
    int h  = nblk >> 1;
    int l0 = (nblk & 1) * 128;
    int t = threadIdx.x;
    int w = t >> 6, lane = t & 63, c = lane & 15, g = lane >> 4;

    __shared__ f16 Ao[64 * APAD];
    #pragma unroll
    for (int it = 0; it < 16; ++it) {
        int idx4 = it * 256 + t;
        int s = idx4 >> 6, kq = idx4 & 63;
        float4 v = *(const float4*)(x + (size_t)(b0 + s) * (NSEQ * ND) + kq * 4);
        *(f16x4*)(&Ao[s * APAD + kq * 4]) = (f16x4){(f16)v.x, (f16)v.y, (f16)v.z, (f16)v.w};
    }
    __syncthreads();

    f32x4 acc[4][2];
    #pragma unroll
    for (int mt = 0; mt < 4; ++mt)
        #pragma unroll
        for (int nt = 0; nt < 2; ++nt) acc[mt][nt] = (f32x4){0.f, 0.f, 0.f, 0.f};

    const f16* bb = wh + ((size_t)((h * 3 + 2) * 256 + l0 + w * 32 + c)) * 256;
    #pragma unroll 2
    for (int kk = 0; kk < 8; ++kk) {
        int k0 = kk * 32 + g * 8;
        f16x8 af[4];
        #pragma unroll
        for (int mt = 0; mt < 4; ++mt)
            af[mt] = *(const f16x8*)(&Ao[(mt * 16 + c) * APAD + k0]);
        #pragma unroll
        for (int nt = 0; nt < 2; ++nt) {
            f16x8 bf = *(const f16x8*)(bb + nt * 16 * 256 + k0);
            #pragma unroll
            for (int mt = 0; mt < 4; ++mt)
                acc[mt][nt] = __builtin_amdgcn_mfma_f32_16x16x32_f16(af[mt], bf, acc[mt][nt], 0, 0, 0);
        }
    }
    #pragma unroll
    for (int mt = 0; mt < 4; ++mt)
        #pragma unroll
        for (int nt = 0; nt < 2; ++nt)
            #pragma unroll
            for (int r = 0; r < 4; ++r)
                OK[((size_t)h * NB + b0 + mt * 16 + g * 4 + r) * NL + l0 + w * 32 + nt * 16 + c]
                    = acc[mt][nt][r];
}

// ---------------------------------------------------------------------------
// Main fused kernel: one block per batch, 8 heads looped over one A-tile.
// Per head: q-GEMM -> q-epi (redp[h&1]) -> v-GEMM -> ONE barrier ->
//           distributed per-wave softmax -> v-epi.  redp ping-pong removes
//           the second barrier; no wave-0 serialization anywhere.
// ---------------------------------------------------------------------------
__global__ __launch_bounds__(256, 3) void attn_mfma(
        const float* __restrict__ x,
        const f16*   __restrict__ wh,
        const float* __restrict__ W,
        const float* __restrict__ bias,
        const float* __restrict__ PKT,
        const float* __restrict__ OK,
        f16* __restrict__ res) {
    int b = blockIdx.x;
    int t = threadIdx.x;
    int w    = t >> 6;
    int lane = t & 63;
    int c = lane & 15;
    int g = lane >> 4;

    __shared__ f16 A[NS * APAD];         // 33792 B walk tile (shared by 8 heads)
    __shared__ float redp[2][4][NS];     // 2048 B ping-pong score partials

    const float* xb = x + (size_t)b * (NSEQ * ND);

    // --- stage A (walk) once ----------------------------------------------
    #pragma unroll
    for (int it = 0; it < 16; ++it) {
        int idx4 = it * 256 + t;
        int s  = idx4 >> 6;
        int kq = idx4 & 63;
        float4 v = *(const float4*)(xb + (1 + s) * ND + kq * 4);
        *(f16x4*)(&A[s * APAD + kq * 4]) = (f16x4){(f16)v.x, (f16)v.y, (f16)v.z, (f16)v.w};
    }
    __syncthreads();

    for (int h = 0; h < NH; ++h) {
        int p = h & 1;
        const f16* bq = wh + ((size_t)((h * 3 + 0) * 256 + w * 64 + c)) * 256;
        const f16* bv = wh + ((size_t)((h * 3 + 1) * 256 + w * 64 + c)) * 256;

        // --- phase 1: q-GEMM (128 MFMA) ------------------------------------
        f32x4 acc[4][4];
        #pragma unroll
        for (int mt = 0; mt < 4; ++mt)
            #pragma unroll
            for (int nt = 0; nt < 4; ++nt) acc[mt][nt] = (f32x4){0.f, 0.f, 0.f, 0.f};

        #pragma unroll 2
        for (int kk = 0; kk < 8; ++kk) {
            int k0 = kk * 32 + g * 8;
            f16x8 af[4];
            #pragma unroll
            for (int mt = 0; mt < 4; ++mt)
                af[mt] = *(const f16x8*)(&A[(mt * 16 + c) * APAD + k0]);
            #pragma unroll
            for (int nt = 0; nt < 4; ++nt) {
                f16x8 bfq = *(const f16x8*)(bq + nt * 16 * 256 + k0);
                #pragma unroll
                for (int mt = 0; mt < 4; ++mt)
                    acc[mt][nt] = __builtin_amdgcn_mfma_f32_16x16x32_f16(af[mt], bfq, acc[mt][nt], 0, 0, 0);
            }
        }

        // --- q epilogue: edge -> per-wave score partials -------------------
        float bh = bias[h];
        float wl[4], okv[4];
        #pragma unroll
        for (int nt = 0; nt < 4; ++nt) {
            wl[nt]  = W[h * NL + w * 64 + nt * 16 + c];
            okv[nt] = OK[((size_t)h * NB + b) * NL + w * 64 + nt * 16 + c];
        }
        float part[4][4];
        #pragma unroll
        for (int mt = 0; mt < 4; ++mt)
            #pragma unroll
            for (int r = 0; r < 4; ++r) part[mt][r] = 0.f;

        const float* PKTp = PKT + ((size_t)h * NL + w * 64 + c) * NS + g * 4;
        #pragma unroll
        for (int nt = 0; nt < 4; ++nt) {
            const float* pkcol = PKTp + (size_t)nt * 16 * NS;
            float4 pk4[4];
            #pragma unroll
            for (int mt = 0; mt < 4; ++mt) pk4[mt] = *(const float4*)(pkcol + mt * 16);
            #pragma unroll
            for (int mt = 0; mt < 4; ++mt) {
                float pks[4] = {pk4[mt].x, pk4[mt].y, pk4[mt].z, pk4[mt].w};
                #pragma unroll
                for (int r = 0; r < 4; ++r) {
                    float qs = sigmoidf_(acc[mt][nt][r]);
                    float ks = sigmoidf_(okv[nt] + pks[r]);
                    part[mt][r] = fmaf(__cosf(ks * qs) + bh, wl[nt], part[mt][r]);
                }
            }
        }
        #pragma unroll
        for (int mt = 0; mt < 4; ++mt) {
            #pragma unroll
            for (int r = 0; r < 4; ++r) {
                float v = part[mt][r];
                v += __shfl_xor(v, 1, 64);
                v += __shfl_xor(v, 2, 64);
                v += __shfl_xor(v, 4, 64);
                v += __shfl_xor(v, 8, 64);
                if (c == 0) redp[p][w][mt * 16 + g * 4 + r] = v;
            }
        }

        // --- phase 2: v-GEMM (accs reused) ---------------------------------
        #pragma unroll
        for (int mt = 0; mt < 4; ++mt)
            #pragma unroll
            for (int nt = 0; nt < 4; ++nt) acc[mt][nt] = (f32x4){0.f, 0.f, 0.f, 0.f};
        #pragma unroll 2
        for (int kk = 0; kk < 8; ++kk) {
            int k0 = kk * 32 + g * 8;
            f16x8 af[4];
            #pragma unroll
            for (int mt = 0; mt < 4; ++mt)
                af[mt] = *(const f16x8*)(&A[(mt * 16 + c) * APAD + k0]);
            #pragma unroll
            for (int nt = 0; nt < 4; ++nt) {
                f16x8 bfv = *(const f16x8*)(bv + nt * 16 * 256 + k0);
                #pragma unroll
                for (int mt = 0; mt < 4; ++mt)
                    acc[mt][nt] = __builtin_amdgcn_mfma_f32_16x16x32_f16(af[mt], bfv, acc[mt][nt], 0, 0, 0);
            }
        }
        __syncthreads();                  // redp[p] complete for all waves

        // --- distributed softmax (every wave, no serialization) ------------
        f32x4 sc4[4];
        #pragma unroll
        for (int mt = 0; mt < 4; ++mt) {
            int so = mt * 16 + g * 4;
            float4 a0 = *(const float4*)(&redp[p][0][so]);   // broadcast reads
            float4 a1 = *(const float4*)(&redp[p][1][so]);
            float4 a2 = *(const float4*)(&redp[p][2][so]);
            float4 a3 = *(const float4*)(&redp[p][3][so]);
            sc4[mt] = (f32x4){a0.x + a1.x + a2.x + a3.x,
                              a0.y + a1.y + a2.y + a3.y,
                              a0.z + a1.z + a2.z + a3.z,
                              a0.w + a1.w + a2.w + a3.w};
        }
        float m = sc4[0][0];
        #pragma unroll
        for (int mt = 0; mt < 4; ++mt)
            #pragma unroll
            for (int r = 0; r < 4; ++r) m = fmaxf(m, sc4[mt][r]);
        m = fmaxf(m, __shfl_xor(m, 16, 64));
        m = fmaxf(m, __shfl_xor(m, 32, 64));
        float ps[4][4];
        float ssum = 0.f;
        #pragma unroll
        for (int mt = 0; mt < 4; ++mt)
            #pragma unroll
            for (int r = 0; r < 4; ++r) {
                float e = __expf(sc4[mt][r] - m);
                ps[mt][r] = e;
                ssum += e;
            }
        ssum += __shfl_xor(ssum, 16, 64);
        ssum += __shfl_xor(ssum, 32, 64);
        float rinv = __builtin_amdgcn_rcpf(ssum);
        #pragma unroll
        for (int mt = 0; mt < 4; ++mt)
            #pragma unroll
            for (int r = 0; r < 4; ++r) ps[mt][r] *= rinv;

        // --- v epilogue: res f16 -------------------------------------------
        #pragma unroll
        for (int nt = 0; nt < 4; ++nt) {
            float v = 0.f;
            #pragma unroll
            for (int mt = 0; mt < 4; ++mt)
                #pragma unroll
                for (int r = 0; r < 4; ++r)
                    v = fmaf(ps[mt][r], sigmoidf_(acc[mt][nt][r]), v);
            v += __shfl_xor(v, 16, 64);
            v += __shfl_xor(v, 32, 64);
            if (g == 0)
                res[(size_t)b * 2048 + h * NL + w * 64 + nt * 16 + c] = (f16)v;
        }
    }
}

// ---------------------------------------------------------------------------
// out GEMM: out[b][0:256] = sigmoid(res[b] @ O)  (f16 MFMA, K=2048)
// ---------------------------------------------------------------------------
__global__ __launch_bounds__(256) void out_gemm(
        const float* __restrict__ x,
        const f16*   __restrict__ res,
        const f16*   __restrict__ OT,
        float* __restrict__ out) {
    int mblk = blockIdx.x >> 1;
    int nblk = blockIdx.x & 1;
    int b0 = mblk * 64;
    int t  = threadIdx.x;
    int w    = t >> 6;
    int lane = t & 63;
    int c = lane & 15;
    int g = lane >> 4;

    __shared__ f16 Ao[64 * APAD];

    f32x4 acc[4][2];
    #pragma unroll
    for (int mt = 0; mt < 4; ++mt)
        #pragma unroll
        for (int nt = 0; nt < 2; ++nt) acc[mt][nt] = (f32x4){0.f, 0.f, 0.f, 0.f};

    for (int chunk = 0; chunk < 8; ++chunk) {
        int kbase = chunk * 256;
        __syncthreads();
        #pragma unroll
        for (int it = 0; it < 8; ++it) {
            int id  = it * 256 + t;
            int row = id >> 5;
            int kc  = (id & 31) << 3;
            *(f16x8*)(&Ao[row * APAD + kc]) =
                *(const f16x8*)(res + (size_t)(b0 + row) * 2048 + kbase + kc);
        }
        __syncthreads();
        #pragma unroll
        for (int kk = 0; kk < 8; ++kk) {
            int k0 = kk * 32 + g * 8;
            f16x8 af[4];
            #pragma unroll
            for (int mt = 0; mt < 4; ++mt)
                af[mt] = *(const f16x8*)(&Ao[(mt * 16 + c) * APAD + k0]);
            #pragma unroll
            for (int nt = 0; nt < 2; ++nt) {
                f16x8 bf = *(const f16x8*)(OT + (size_t)(nblk * 128 + w * 32 + nt * 16 + c) * 2048 + kbase + k0);
                #pragma unroll
                for (int mt = 0; mt < 4; ++mt)
                    acc[mt][nt] = __builtin_amdgcn_mfma_f32_16x16x32_f16(af[mt], bf, acc[mt][nt], 0, 0, 0);
            }
        }
    }
    #pragma unroll
    for (int mt = 0; mt < 4; ++mt)
        #pragma unroll
        for (int nt = 0; nt < 2; ++nt)
            #pragma unroll
            for (int r = 0; r < 4; ++r) {
                int row = mt * 16 + g * 4 + r;
                int col = nblk * 128 + w * 32 + nt * 16 + c;
                out[(size_t)(b0 + row) * 512 + col] = sigmoidf_(acc[mt][nt][r]);
            }
    if (nblk == 1) {                     // origin passthrough for these 64 rows
        for (int r2 = 0; r2 < 64; ++r2)
            out[(size_t)(b0 + r2) * 512 + 256 + t] = x[(size_t)(b0 + r2) * (NSEQ * ND) + t];
    }
}

// ---------------------------------------------------------------------------
extern "C" void kernel_launch(void* const* d_in, const int* in_sizes, int n_in,
                              void* d_out, int out_size, void* d_ws, size_t ws_size,
                              hipStream_t stream) {
    const float* x    = (const float*)d_in[0];
    const float* Wq   = (const float*)d_in[1];
    const float* Wk   = (const float*)d_in[2];
    const float* Wv   = (const float*)d_in[3];
    const float* W    = (const float*)d_in[4];
    const float* O    = (const float*)d_in[5];
    const float* P    = (const float*)d_in[6];
    const float* bias = (const float*)d_in[7];
    float* out = (float*)d_out;

    // ws carve: wh 3MB | OT 1MB | PKT 512KB | OK 16MB | res 8MB  (~28.5MB)
    char* wsb = (char*)d_ws;
    f16*   wh  = (f16*)wsb;                       // 3*8*256*256 f16 = 3145728 B
    f16*   OT  = (f16*)(wsb + 3145728);           // 256*2048 f16   = 1048576 B
    float* PKT = (float*)(wsb + 4194304);         // 8*256*64 f32   = 524288 B
    float* OK  = (float*)(wsb + 4718592);         // 8*2048*256 f32 = 16777216 B
    f16*   res = (f16*)(wsb + 21495808);          // 2048*2048 f16  = 8388608 B

    wh_kernel<<<384, 256, 0, stream>>>(Wq, Wv, Wk, wh);
    ot_kernel<<<256, 256, 0, stream>>>(O, OT);
    pkt_kernel<<<NH * NS, 256, 0, stream>>>(P, Wk, PKT);
    ok_gemm<<<512, 256, 0, stream>>>(x, wh, OK);
    attn_mfma<<<NB, 256, 0, stream>>>(x, wh, W, bias, PKT, OK, res);
    out_gemm<<<64, 256, 0, stream>>>(x, res, OT, out);
}